// Round 2
// baseline (2762.835 us; speedup 1.0000x reference)
//
#include <hip/hip_runtime.h>
#include <math.h>

// Dims: V=50000 F=300 H=256 P=128 C=10  B=128 S=16 N=64  G=2048 T=131072

typedef unsigned short u16;

__device__ __forceinline__ float b2f(u16 v) {
    return __uint_as_float(((unsigned)v) << 16);
}
__device__ __forceinline__ u16 f2b(float f) {
    unsigned u = __float_as_uint(f);
    return (u16)((u + 0x7FFFu + ((u >> 16) & 1u)) >> 16);   // RNE
}

// LDS layout for the per-graph megakernel (53,504 B total)
struct Smem {
    u16 S[64][260];     // hidden panel (bf16), row stride 520B
    u16 adjS[64][68];   // adjacency (bf16)
    u16 wt[16][264];    // streamed weight K-tile (bf16)
    u16 ht[64][20];     // gathered embedding K-tile (bf16)
    float logits[64];
    float alpha[64];
};

// acc[4][16]: thread (tx,ty) owns rows ty*4+i, cols tx*4 + jj*64 + q
__device__ __forceinline__ void write_acc(Smem& sm, float acc[4][16],
    const float* bias, bool relu, int tx, int ty)
{
    #pragma unroll
    for (int i = 0; i < 4; ++i) {
        int r = ty * 4 + i;
        #pragma unroll
        for (int jj = 0; jj < 4; ++jj) {
            int c = tx * 4 + jj * 64;
            float v[4];
            #pragma unroll
            for (int q = 0; q < 4; ++q) {
                float t = acc[i][jj * 4 + q];
                if (bias) t += bias[c + q];
                if (relu) t = fmaxf(t, 0.f);
                v[q] = t;
            }
            ushort4 o;
            o.x = f2b(v[0]); o.y = f2b(v[1]); o.z = f2b(v[2]); o.w = f2b(v[3]);
            *(ushort4*)&sm.S[r][c] = o;
        }
    }
}

// acc = S @ W  (K=256), W f32 row-major (256,256) streamed via sm.wt
__device__ __forceinline__ void mmS(Smem& sm, const float* __restrict__ W,
    float acc[4][16], int tx, int ty, int tid)
{
    #pragma unroll
    for (int i = 0; i < 4; ++i)
        #pragma unroll
        for (int j = 0; j < 16; ++j) acc[i][j] = 0.f;

    for (int k0 = 0; k0 < 256; k0 += 16) {
        int kr = tid >> 4, cc = (tid & 15) * 16;
        const float* wrow = &W[(long)(k0 + kr) * 256 + cc];
        #pragma unroll
        for (int q = 0; q < 4; ++q) {
            float4 v = *(const float4*)&wrow[q * 4];
            ushort4 o; o.x = f2b(v.x); o.y = f2b(v.y); o.z = f2b(v.z); o.w = f2b(v.w);
            *(ushort4*)&sm.wt[kr][cc + q * 4] = o;
        }
        __syncthreads();
        #pragma unroll
        for (int kk = 0; kk < 16; ++kk) {
            float a[4];
            #pragma unroll
            for (int i = 0; i < 4; ++i) a[i] = b2f(sm.S[ty * 4 + i][k0 + kk]);
            #pragma unroll
            for (int jj = 0; jj < 4; ++jj) {
                ushort4 bv = *(const ushort4*)&sm.wt[kk][tx * 4 + jj * 64];
                float b0 = b2f(bv.x), b1 = b2f(bv.y), b2v = b2f(bv.z), b3 = b2f(bv.w);
                #pragma unroll
                for (int i = 0; i < 4; ++i) {
                    acc[i][jj * 4 + 0] += a[i] * b0;
                    acc[i][jj * 4 + 1] += a[i] * b1;
                    acc[i][jj * 4 + 2] += a[i] * b2v;
                    acc[i][jj * 4 + 3] += a[i] * b3;
                }
            }
        }
        __syncthreads();
    }
}

// S <- relu(adj @ S + bias)
__device__ __forceinline__ void adj_step(Smem& sm, const float* bias,
    float acc[4][16], int tx, int ty)
{
    #pragma unroll
    for (int i = 0; i < 4; ++i)
        #pragma unroll
        for (int j = 0; j < 16; ++j) acc[i][j] = 0.f;

    #pragma unroll 8
    for (int kk = 0; kk < 64; ++kk) {
        float a[4];
        #pragma unroll
        for (int i = 0; i < 4; ++i) a[i] = b2f(sm.adjS[ty * 4 + i][kk]);
        #pragma unroll
        for (int jj = 0; jj < 4; ++jj) {
            ushort4 bv = *(const ushort4*)&sm.S[kk][tx * 4 + jj * 64];
            float b0 = b2f(bv.x), b1 = b2f(bv.y), b2v = b2f(bv.z), b3 = b2f(bv.w);
            #pragma unroll
            for (int i = 0; i < 4; ++i) {
                acc[i][jj * 4 + 0] += a[i] * b0;
                acc[i][jj * 4 + 1] += a[i] * b1;
                acc[i][jj * 4 + 2] += a[i] * b2v;
                acc[i][jj * 4 + 3] += a[i] * b3;
            }
        }
    }
    __syncthreads();
    write_acc(sm, acc, bias, true, tx, ty);
    __syncthreads();
}

// masked attention pool: logits over rows 0..62 of relu(S@aw+ab)·av,
// pooled over rows 0..62 of S, master = row 63. Writes z[g, zoff:zoff+512].
__device__ __forceinline__ void attention(Smem& sm, const float* aw, const float* ab,
    const float* av, float* z, int g, int zoff, int tx, int ty, int tid, float acc[4][16])
{
    mmS(sm, aw, acc, tx, ty, tid);
    float p[4] = {0.f, 0.f, 0.f, 0.f};
    #pragma unroll
    for (int jj = 0; jj < 4; ++jj) {
        int c = tx * 4 + jj * 64;
        #pragma unroll
        for (int q = 0; q < 4; ++q) {
            float abv = ab[c + q], avv = av[c + q];
            #pragma unroll
            for (int i = 0; i < 4; ++i) {
                float u = fmaxf(acc[i][jj * 4 + q] + abv, 0.f);
                p[i] += u * avv;
            }
        }
    }
    #pragma unroll
    for (int i = 0; i < 4; ++i) {
        float pi = p[i];
        pi += __shfl_xor(pi, 8, 16);
        pi += __shfl_xor(pi, 4, 16);
        pi += __shfl_xor(pi, 2, 16);
        pi += __shfl_xor(pi, 1, 16);
        if (tx == 0) sm.logits[ty * 4 + i] = pi;
    }
    __syncthreads();
    if (tid < 64) {
        float v = (tid < 63) ? sm.logits[tid] : -INFINITY;
        float m = v;
        #pragma unroll
        for (int off = 32; off; off >>= 1) m = fmaxf(m, __shfl_xor(m, off, 64));
        float e = (tid < 63) ? expf(v - m) : 0.f;
        float s = e;
        #pragma unroll
        for (int off = 32; off; off >>= 1) s += __shfl_xor(s, off, 64);
        sm.alpha[tid] = e / s;
    }
    __syncthreads();
    float pool = 0.f;
    for (int r = 0; r < 63; ++r) pool += sm.alpha[r] * b2f(sm.S[r][tid]);
    long zb = (long)g * 1024 + zoff;
    z[zb + tid] = pool;
    z[zb + 256 + tid] = b2f(sm.S[63][tid]);
    __syncthreads();
}

// ---------------------------------------------------------------------------
// One block per graph: emb-gather GEMM -> adj -> w2 -> att0 -> w1' -> adj ->
// w2' -> att1, hidden panel resident in LDS. Writes z[g, 0:1024].
// ---------------------------------------------------------------------------
__global__ __launch_bounds__(256) void graph_mega_k(
    const int* __restrict__ x, const float* __restrict__ adj,
    const float* __restrict__ emb,
    const float* __restrict__ w1a, const float* __restrict__ b1a,
    const float* __restrict__ w2a, const float* __restrict__ b2a,
    const float* __restrict__ awa, const float* __restrict__ aba, const float* __restrict__ ava,
    const float* __restrict__ w1b, const float* __restrict__ b1b,
    const float* __restrict__ w2b, const float* __restrict__ b2b,
    const float* __restrict__ awb, const float* __restrict__ abb, const float* __restrict__ avb,
    float* __restrict__ z)
{
    __shared__ Smem sm;
    const int g = blockIdx.x;
    const int tid = threadIdx.x;
    const int tx = tid & 15, ty = tid >> 4;

    // stage adj[g] (64x64) -> bf16
    {
        int r = tid >> 2, c0 = (tid & 3) * 16;
        const float* ap = &adj[((long)g * 64 + r) * 64 + c0];
        #pragma unroll
        for (int q = 0; q < 4; ++q) {
            float4 v = *(const float4*)&ap[q * 4];
            sm.adjS[r][c0 + q * 4 + 0] = f2b(v.x);
            sm.adjS[r][c0 + q * 4 + 1] = f2b(v.y);
            sm.adjS[r][c0 + q * 4 + 2] = f2b(v.z);
            sm.adjS[r][c0 + q * 4 + 3] = f2b(v.w);
        }
    }

    float acc[4][16];
    // ---- step A: S = emb[x_g] @ w1a   (64x300 @ 300x256), K streamed
    #pragma unroll
    for (int i = 0; i < 4; ++i)
        #pragma unroll
        for (int j = 0; j < 16; ++j) acc[i][j] = 0.f;

    const long xrow = (long)x[g * 64 + (tid >> 2)] * 300;  // gather row for staging
    for (int k0 = 0; k0 < 300; k0 += 16) {
        {   // stage h-tile (64 x 16)
            int c = (tid & 3) * 4;
            int kg = k0 + c;
            float4 v = make_float4(0.f, 0.f, 0.f, 0.f);
            if (kg < 300) v = *(const float4*)&emb[xrow + kg];
            int r = tid >> 2;
            sm.ht[r][c + 0] = f2b(v.x);
            sm.ht[r][c + 1] = f2b(v.y);
            sm.ht[r][c + 2] = f2b(v.z);
            sm.ht[r][c + 3] = f2b(v.w);
        }
        {   // stage w1a tile (16 x 256)
            int kr = tid >> 4, cc = (tid & 15) * 16;
            int kg = k0 + kr;
            #pragma unroll
            for (int q = 0; q < 4; ++q) {
                float4 v = make_float4(0.f, 0.f, 0.f, 0.f);
                if (kg < 300) v = *(const float4*)&w1a[(long)kg * 256 + cc + q * 4];
                ushort4 o; o.x = f2b(v.x); o.y = f2b(v.y); o.z = f2b(v.z); o.w = f2b(v.w);
                *(ushort4*)&sm.wt[kr][cc + q * 4] = o;
            }
        }
        __syncthreads();
        #pragma unroll
        for (int kk = 0; kk < 16; ++kk) {
            float a[4];
            #pragma unroll
            for (int i = 0; i < 4; ++i) a[i] = b2f(sm.ht[ty * 4 + i][kk]);
            #pragma unroll
            for (int jj = 0; jj < 4; ++jj) {
                ushort4 bv = *(const ushort4*)&sm.wt[kk][tx * 4 + jj * 64];
                float b0 = b2f(bv.x), b1 = b2f(bv.y), b2v = b2f(bv.z), b3 = b2f(bv.w);
                #pragma unroll
                for (int i = 0; i < 4; ++i) {
                    acc[i][jj * 4 + 0] += a[i] * b0;
                    acc[i][jj * 4 + 1] += a[i] * b1;
                    acc[i][jj * 4 + 2] += a[i] * b2v;
                    acc[i][jj * 4 + 3] += a[i] * b3;
                }
            }
        }
        __syncthreads();
    }
    write_acc(sm, acc, nullptr, false, tx, ty);     // S = P  (no bias/relu)
    __syncthreads();

    // ---- step B: S = relu(adj @ S + b1a)
    adj_step(sm, b1a, acc, tx, ty);
    // ---- step C: S = relu(S @ w2a + b2a)
    mmS(sm, w2a, acc, tx, ty, tid);
    write_acc(sm, acc, b2a, true, tx, ty);
    __syncthreads();
    // ---- step D: attention 0 -> z[g, 0:512]
    attention(sm, awa, aba, ava, z, g, 0, tx, ty, tid, acc);
    // ---- step E: S = S @ w1b  (no bias/relu)
    mmS(sm, w1b, acc, tx, ty, tid);
    write_acc(sm, acc, nullptr, false, tx, ty);
    __syncthreads();
    // ---- step F: S = relu(adj @ S + b1b)
    adj_step(sm, b1b, acc, tx, ty);
    // ---- step G: S = relu(S @ w2b + b2b)
    mmS(sm, w2b, acc, tx, ty, tid);
    write_acc(sm, acc, b2b, true, tx, ty);
    __syncthreads();
    // ---- step H: attention 1 -> z[g, 512:1024]
    attention(sm, awb, abb, avb, z, g, 512, tx, ty, tid, acc);
}

// ---------------------------------------------------------------------------
// BatchNorm stats over rows of z (2048 x 1024): scale/shift per column.
// ---------------------------------------------------------------------------
__global__ __launch_bounds__(256) void bnstats_k(
    const float* __restrict__ z, const float* __restrict__ gamma,
    const float* __restrict__ beta,
    float* __restrict__ scale, float* __restrict__ shift)
{
    const int c0 = blockIdx.x * 16;
    const int tid = threadIdx.x;
    const int c = c0 + (tid & 15), ph = tid >> 4;
    double s = 0.0, s2 = 0.0;
    for (int r = ph; r < 2048; r += 16) {
        float v = z[(long)r * 1024 + c];
        s += v; s2 += (double)v * v;
    }
    __shared__ double ss[16][17], ss2[16][17];
    ss[ph][tid & 15] = s; ss2[ph][tid & 15] = s2;
    __syncthreads();
    if (ph == 0) {
        double ts = 0.0, ts2 = 0.0;
        #pragma unroll
        for (int i = 0; i < 16; ++i) { ts += ss[i][tid & 15]; ts2 += ss2[i][tid & 15]; }
        double mu = ts / 2048.0;
        double var = ts2 / 2048.0 - mu * mu;
        float inv = (float)(1.0 / sqrt(var + 1e-5));
        float sc = gamma[c] * inv;
        scale[c] = sc;
        shift[c] = beta[c] - (float)mu * sc;
    }
}

// ---------------------------------------------------------------------------
// fc1: z2 = relu((z*scale+shift) @ fc1_w + fc1_b)   (2048x1024 @ 1024x256)
// BM=BN=64, BK=16 tiled fp32 GEMM.
// ---------------------------------------------------------------------------
__global__ __launch_bounds__(256) void fc1_k(
    const float* __restrict__ A, const float* __restrict__ W,
    const float* __restrict__ bias, float* __restrict__ C,
    const float* __restrict__ scale, const float* __restrict__ shift)
{
    const int M = 2048, N = 256, K = 1024;
    __shared__ float As[16][68];
    __shared__ float Bs[16][68];
    const int tid = threadIdx.x;
    const int tx = tid & 15, ty = tid >> 4;
    const int n0 = blockIdx.x * 64, m0 = blockIdx.y * 64;
    const int li = tid >> 2, lk4 = tid & 3;
    const int bkk = tid >> 4, bj4 = tid & 15;
    const long arow = (long)(m0 + li) * K;

    float acc[4][4] = {};
    for (int k0 = 0; k0 < K; k0 += 16) {
        int kg = k0 + lk4 * 4;
        float4 av = *(const float4*)&A[arow + kg];
        float4 sc = *(const float4*)&scale[kg];
        float4 sh = *(const float4*)&shift[kg];
        av.x = av.x * sc.x + sh.x;
        av.y = av.y * sc.y + sh.y;
        av.z = av.z * sc.z + sh.z;
        av.w = av.w * sc.w + sh.w;
        As[lk4 * 4 + 0][li] = av.x;
        As[lk4 * 4 + 1][li] = av.y;
        As[lk4 * 4 + 2][li] = av.z;
        As[lk4 * 4 + 3][li] = av.w;
        float4 bv = *(const float4*)&W[(long)(k0 + bkk) * N + n0 + bj4 * 4];
        *(float4*)&Bs[bkk][bj4 * 4] = bv;
        __syncthreads();
        #pragma unroll
        for (int kk = 0; kk < 16; ++kk) {
            float4 a = *(const float4*)&As[kk][ty * 4];
            float4 b = *(const float4*)&Bs[kk][tx * 4];
            float ar[4] = {a.x, a.y, a.z, a.w};
            float br[4] = {b.x, b.y, b.z, b.w};
            #pragma unroll
            for (int i = 0; i < 4; ++i)
                #pragma unroll
                for (int j = 0; j < 4; ++j)
                    acc[i][j] += ar[i] * br[j];
        }
        __syncthreads();
    }
    #pragma unroll
    for (int i = 0; i < 4; ++i) {
        int r = m0 + ty * 4 + i;
        float v[4];
        #pragma unroll
        for (int j = 0; j < 4; ++j)
            v[j] = fmaxf(acc[i][j] + bias[n0 + tx * 4 + j], 0.f);
        *(float4*)&C[(long)r * N + n0 + tx * 4] = make_float4(v[0], v[1], v[2], v[3]);
    }
}

// ---------------------------------------------------------------------------
// Segment attention (no master) over z2 (128 x 16 x 256) -> pooled (128x256)
// ---------------------------------------------------------------------------
__global__ __launch_bounds__(256) void satt_k(
    const float* __restrict__ z2, const float* __restrict__ sw,
    const float* __restrict__ sb, const float* __restrict__ sv,
    float* __restrict__ pooled)
{
    const int b = blockIdx.x;
    const int tid = threadIdx.x;
    __shared__ float zs[16][256];
    for (int idx = tid; idx < 16 * 256; idx += 256) {
        int r = idx >> 8, c = idx & 255;
        zs[r][c] = z2[((long)b * 16 + r) * 256 + c];
    }
    __syncthreads();

    float acc[16] = {};
    for (int k = 0; k < 256; ++k) {
        float w = sw[k * 256 + tid];
        #pragma unroll
        for (int r = 0; r < 16; ++r) acc[r] += zs[r][k] * w;
    }
    const float sbv = sb[tid], svv = sv[tid];

    __shared__ float red[16][4];
    __shared__ float logit_s[16], alpha_s[16];
    const int warp = tid >> 6, lane = tid & 63;
    #pragma unroll
    for (int r = 0; r < 16; ++r) {
        float u = fmaxf(acc[r] + sbv, 0.f);
        float lv = u * svv;
        #pragma unroll
        for (int off = 32; off; off >>= 1) lv += __shfl_down(lv, off, 64);
        if (lane == 0) red[r][warp] = lv;
    }
    __syncthreads();
    if (tid < 16) logit_s[tid] = red[tid][0] + red[tid][1] + red[tid][2] + red[tid][3];
    __syncthreads();
    if (tid < 16) {
        float m = -INFINITY;
        #pragma unroll
        for (int i = 0; i < 16; ++i) m = fmaxf(m, logit_s[i]);
        float ssum = 0.f;
        #pragma unroll
        for (int i = 0; i < 16; ++i) ssum += expf(logit_s[i] - m);
        alpha_s[tid] = expf(logit_s[tid] - m) / ssum;
    }
    __syncthreads();
    float pacc = 0.f;
    #pragma unroll
    for (int r = 0; r < 16; ++r) pacc += alpha_s[r] * zs[r][tid];
    pooled[(long)b * 256 + tid] = pacc;
}

// ---------------------------------------------------------------------------
// Final head: relu(pooled@fc2+b2) -> @fc3+b3 -> log_softmax
// ---------------------------------------------------------------------------
__global__ __launch_bounds__(128) void final_k(
    const float* __restrict__ pooled,
    const float* __restrict__ w2, const float* __restrict__ b2,
    const float* __restrict__ w3, const float* __restrict__ b3,
    float* __restrict__ out)
{
    const int b = blockIdx.x, tid = threadIdx.x;
    __shared__ float ps[256], z3s[128], z4s[10];
    ps[tid]       = pooled[(long)b * 256 + tid];
    ps[tid + 128] = pooled[(long)b * 256 + tid + 128];
    __syncthreads();
    float acc = b2[tid];
    for (int k = 0; k < 256; ++k) acc += ps[k] * w2[k * 128 + tid];
    z3s[tid] = fmaxf(acc, 0.f);
    __syncthreads();
    if (tid < 10) {
        float a3 = b3[tid];
        for (int k = 0; k < 128; ++k) a3 += z3s[k] * w3[k * 10 + tid];
        z4s[tid] = a3;
    }
    __syncthreads();
    if (tid < 10) {
        float m = z4s[0];
        #pragma unroll
        for (int i = 1; i < 10; ++i) m = fmaxf(m, z4s[i]);
        float s = 0.f;
        #pragma unroll
        for (int i = 0; i < 10; ++i) s += expf(z4s[i] - m);
        out[b * 10 + tid] = z4s[tid] - m - logf(s);
    }
}

// ---------------------------------------------------------------------------
extern "C" void kernel_launch(void* const* d_in, const int* in_sizes, int n_in,
                              void* d_out, int out_size, void* d_ws, size_t ws_size,
                              hipStream_t stream)
{
    const int*   x      = (const int*)d_in[0];
    const float* adj    = (const float*)d_in[1];
    // d_in[2] = adj_s (unused by reference), d_in[3]/d_in[4] = shape scalars
    const float* emb    = (const float*)d_in[5];
    const float* mp0_w1 = (const float*)d_in[6];
    const float* mp0_b1 = (const float*)d_in[7];
    const float* mp0_w2 = (const float*)d_in[8];
    const float* mp0_b2 = (const float*)d_in[9];
    const float* mp1_w1 = (const float*)d_in[10];
    const float* mp1_b1 = (const float*)d_in[11];
    const float* mp1_w2 = (const float*)d_in[12];
    const float* mp1_b2 = (const float*)d_in[13];
    const float* att0_w = (const float*)d_in[14];
    const float* att0_b = (const float*)d_in[15];
    const float* att0_v = (const float*)d_in[16];
    const float* att1_w = (const float*)d_in[17];
    const float* att1_b = (const float*)d_in[18];
    const float* att1_v = (const float*)d_in[19];
    const float* bn_g   = (const float*)d_in[20];
    const float* bn_b   = (const float*)d_in[21];
    const float* fc1_w  = (const float*)d_in[22];
    const float* fc1_b  = (const float*)d_in[23];
    const float* satt_w = (const float*)d_in[24];
    const float* satt_b = (const float*)d_in[25];
    const float* satt_v = (const float*)d_in[26];
    const float* fc2_w  = (const float*)d_in[27];
    const float* fc2_b  = (const float*)d_in[28];
    const float* fc3_w  = (const float*)d_in[29];
    const float* fc3_b  = (const float*)d_in[30];
    float* out = (float*)d_out;

    float* ws = (float*)d_ws;
    float* z       = ws;                    // 2048*1024
    float* z2      = z + 2048L * 1024;      // 2048*256
    float* scale   = z2 + 2048L * 256;      // 1024
    float* shiftv  = scale + 1024;          // 1024
    float* pooledS = shiftv + 1024;         // 128*256
    // total ~10.6 MB

    graph_mega_k<<<dim3(2048), dim3(256), 0, stream>>>(
        x, adj, emb,
        mp0_w1, mp0_b1, mp0_w2, mp0_b2, att0_w, att0_b, att0_v,
        mp1_w1, mp1_b1, mp1_w2, mp1_b2, att1_w, att1_b, att1_v, z);

    bnstats_k<<<dim3(64), dim3(256), 0, stream>>>(z, bn_g, bn_b, scale, shiftv);
    fc1_k<<<dim3(4, 32), dim3(256), 0, stream>>>(z, fc1_w, fc1_b, z2, scale, shiftv);
    satt_k<<<dim3(128), dim3(256), 0, stream>>>(z2, satt_w, satt_b, satt_v, pooledS);
    final_k<<<dim3(128), dim3(128), 0, stream>>>(pooledS, fc2_w, fc2_b, fc3_w, fc3_b, out);
}

// Round 4
// 492.394 us; speedup vs baseline: 5.6110x; 5.6110x over previous
//
#include <hip/hip_runtime.h>
#include <math.h>

// Dims: V=50000 F=300 H=256 P=128 C=10  B=128 S=16 N=64  G=2048 T=131072

typedef unsigned short u16;
typedef __attribute__((ext_vector_type(8))) short bf16x8;
typedef __attribute__((ext_vector_type(4))) float f32x4;

__device__ __forceinline__ float b2f(u16 v){ return __uint_as_float(((unsigned)v)<<16); }
__device__ __forceinline__ u16 f2b(float f){
    unsigned u = __float_as_uint(f);
    return (u16)((u + 0x7FFFu + ((u>>16)&1u)) >> 16);   // RNE
}
__device__ __forceinline__ ushort4 pack4(float a,float b,float c,float d){
    ushort4 o; o.x=f2b(a); o.y=f2b(b); o.z=f2b(c); o.w=f2b(d); return o;
}
__device__ __forceinline__ bf16x8 cvt8(float4 lo, float4 hi){
    bf16x8 f;
    f[0]=(short)f2b(lo.x); f[1]=(short)f2b(lo.y); f[2]=(short)f2b(lo.z); f[3]=(short)f2b(lo.w);
    f[4]=(short)f2b(hi.x); f[5]=(short)f2b(hi.y); f[6]=(short)f2b(hi.z); f[7]=(short)f2b(hi.w);
    return f;
}

// LDS: Srow (64 nodes x 256 feat bf16, XOR-swizzled) at 0..32767
//      Scol (256 feat x 64 nodes bf16, XOR-swizzled) at 32768..65535
//      attention scratch (red[4][64], alpha[64]) aliases Scol (dead there).
#define SCOL_OFF 32768
__device__ __forceinline__ int srow_b(int nd, int f){
    return (nd*512 + f*2) ^ ((nd&7)<<4);
}
__device__ __forceinline__ int scol_b(int f, int nd){
    return SCOL_OFF + ((f*128 + nd*2) ^ ((f&7)<<4));
}

// ---------------------------------------------------------------------------
// Megakernel: one block per graph (256 threads = 4 waves). Hidden panel in
// LDS; all GEMMs on MFMA; weights read as bf16 fragments from pre-tiled
// global blobs (no weight LDS, no barriers inside K-loops).
// Weight blob layout (built by conv_wt_k): for ktile t, wave slab w (64 cols),
// u16 chunk at (t*4+w)*2048, element [n_local]*32 + kk  (n=col, kk=k%32).
// ---------------------------------------------------------------------------
__global__ __launch_bounds__(256) void mega_k(
    const int* __restrict__ x, const float* __restrict__ adj,
    const float* __restrict__ emb,
    const u16* __restrict__ wb_w1a, const u16* __restrict__ wb_w2a,
    const u16* __restrict__ wb_awa, const u16* __restrict__ wb_w1b,
    const u16* __restrict__ wb_w2b, const u16* __restrict__ wb_awb,
    const float* __restrict__ b1a, const float* __restrict__ b2a,
    const float* __restrict__ aba, const float* __restrict__ ava,
    const float* __restrict__ b1b, const float* __restrict__ b2b,
    const float* __restrict__ abb, const float* __restrict__ avb,
    float* __restrict__ z)
{
    __shared__ __align__(16) char sm[65536];
    const int g = blockIdx.x, tid = threadIdx.x;
    const int w = tid>>6, l = tid&63, lgp = l>>4, ll = l&15;
    const f32x4 zero4 = {0.f,0.f,0.f,0.f};

    // ---------------- S1: P0 = emb[x_g] @ w1a  -> Scol  (K=320, zero-padded)
    {
        const float* rp[4];
        #pragma unroll
        for (int mi=0;mi<4;++mi) rp[mi] = emb + (long)x[g*64 + mi*16 + ll]*300;
        f32x4 acc[4][4];
        #pragma unroll
        for (int i=0;i<4;++i){
            #pragma unroll
            for (int j=0;j<4;++j) acc[i][j] = zero4;
        }
        for (int t=0;t<10;++t){
            const u16* ch = wb_w1a + ((t*4+w)<<11);
            const int k0 = t*32 + lgp*8;
            bf16x8 a[4], b[4];
            #pragma unroll
            for (int mi=0;mi<4;++mi){
                float4 lo = (k0   < 300) ? *(const float4*)(rp[mi]+k0)   : make_float4(0.f,0.f,0.f,0.f);
                float4 hi = (k0+4 < 300) ? *(const float4*)(rp[mi]+k0+4) : make_float4(0.f,0.f,0.f,0.f);
                a[mi] = cvt8(lo, hi);
            }
            #pragma unroll
            for (int ni=0;ni<4;++ni) b[ni] = *(const bf16x8*)(ch + (ni*16+ll)*32 + lgp*8);
            #pragma unroll
            for (int mi=0;mi<4;++mi){
                #pragma unroll
                for (int ni=0;ni<4;++ni)
                    acc[mi][ni] = __builtin_amdgcn_mfma_f32_16x16x32_bf16(a[mi], b[ni], acc[mi][ni],0,0,0);
            }
        }
        __syncthreads();
        #pragma unroll
        for (int mi=0;mi<4;++mi){
            #pragma unroll
            for (int ni=0;ni<4;++ni){
                int fo = w*64 + ni*16 + ll, nd0 = mi*16 + lgp*4;
                f32x4 v = acc[mi][ni];
                *(ushort4*)(sm + scol_b(fo,nd0)) = pack4(v[0],v[1],v[2],v[3]);
            }
        }
        __syncthreads();
    }

    const float* adjg = adj + (long)g*4096;

    // ========== layer loop (two MP+att layers) ==========
    #pragma unroll 1
    for (int layer=0; layer<2; ++layer){
        const u16* wb_w2 = layer ? wb_w2b : wb_w2a;
        const u16* wb_aw = layer ? wb_awb : wb_awa;
        const float* b1  = layer ? b1b : b1a;
        const float* b2  = layer ? b2b : b2a;
        const float* ab  = layer ? abb : aba;
        const float* av  = layer ? avb : ava;
        const int zoff   = layer ? 512 : 0;

        // ---------- S2: T = relu(adj @ P + b1) : Scol -> Srow (transposed product)
        {
            f32x4 acc[4][4];
            #pragma unroll
            for (int i=0;i<4;++i){
                #pragma unroll
                for (int j=0;j<4;++j) acc[i][j] = zero4;
            }
            #pragma unroll
            for (int t=0;t<2;++t){
                const int k0 = t*32 + lgp*8;
                bf16x8 a[4], b[4];
                #pragma unroll
                for (int mi=0;mi<4;++mi) a[mi] = *(const bf16x8*)(sm + scol_b(w*64+mi*16+ll, k0));
                #pragma unroll
                for (int ni=0;ni<4;++ni){
                    const float* p = adjg + (ni*16+ll)*64 + k0;
                    b[ni] = cvt8(*(const float4*)p, *(const float4*)(p+4));
                }
                #pragma unroll
                for (int mi=0;mi<4;++mi){
                    #pragma unroll
                    for (int ni=0;ni<4;++ni)
                        acc[mi][ni] = __builtin_amdgcn_mfma_f32_16x16x32_bf16(a[mi], b[ni], acc[mi][ni],0,0,0);
                }
            }
            __syncthreads();
            #pragma unroll
            for (int mi=0;mi<4;++mi){
                int f0 = w*64 + mi*16 + lgp*4;
                float4 bi = *(const float4*)(b1 + f0);
                #pragma unroll
                for (int ni=0;ni<4;++ni){
                    int nd = ni*16 + ll;
                    f32x4 v = acc[mi][ni];
                    *(ushort4*)(sm + srow_b(nd, f0)) = pack4(
                        fmaxf(v[0]+bi.x,0.f), fmaxf(v[1]+bi.y,0.f),
                        fmaxf(v[2]+bi.z,0.f), fmaxf(v[3]+bi.w,0.f));
                }
            }
            __syncthreads();
        }

        // ---------- S3: H = relu(T @ w2 + b2) : Srow -> Srow (transposed, in-place)
        {
            f32x4 acc[4][4];
            #pragma unroll
            for (int i=0;i<4;++i){
                #pragma unroll
                for (int j=0;j<4;++j) acc[i][j] = zero4;
            }
            for (int t=0;t<8;++t){
                const u16* ch = wb_w2 + ((t*4+w)<<11);
                const int k0 = t*32 + lgp*8;
                bf16x8 a[4], b[4];
                #pragma unroll
                for (int mi=0;mi<4;++mi) a[mi] = *(const bf16x8*)(ch + (mi*16+ll)*32 + lgp*8);
                #pragma unroll
                for (int ni=0;ni<4;++ni) b[ni] = *(const bf16x8*)(sm + srow_b(ni*16+ll, k0));
                #pragma unroll
                for (int mi=0;mi<4;++mi){
                    #pragma unroll
                    for (int ni=0;ni<4;++ni)
                        acc[mi][ni] = __builtin_amdgcn_mfma_f32_16x16x32_bf16(a[mi], b[ni], acc[mi][ni],0,0,0);
                }
            }
            __syncthreads();
            #pragma unroll
            for (int mi=0;mi<4;++mi){
                int f0 = w*64 + mi*16 + lgp*4;
                float4 bi = *(const float4*)(b2 + f0);
                #pragma unroll
                for (int ni=0;ni<4;++ni){
                    int nd = ni*16 + ll;
                    f32x4 v = acc[mi][ni];
                    *(ushort4*)(sm + srow_b(nd, f0)) = pack4(
                        fmaxf(v[0]+bi.x,0.f), fmaxf(v[1]+bi.y,0.f),
                        fmaxf(v[2]+bi.z,0.f), fmaxf(v[3]+bi.w,0.f));
                }
            }
            __syncthreads();
        }

        // ---------- S4: attention (direct product, U stays in registers)
        {
            f32x4 acc[4][4];
            #pragma unroll
            for (int i=0;i<4;++i){
                #pragma unroll
                for (int j=0;j<4;++j) acc[i][j] = zero4;
            }
            for (int t=0;t<8;++t){
                const u16* ch = wb_aw + ((t*4+w)<<11);
                const int k0 = t*32 + lgp*8;
                bf16x8 a[4], b[4];
                #pragma unroll
                for (int mi=0;mi<4;++mi) a[mi] = *(const bf16x8*)(sm + srow_b(mi*16+ll, k0));
                #pragma unroll
                for (int ni=0;ni<4;++ni) b[ni] = *(const bf16x8*)(ch + (ni*16+ll)*32 + lgp*8);
                #pragma unroll
                for (int mi=0;mi<4;++mi){
                    #pragma unroll
                    for (int ni=0;ni<4;++ni)
                        acc[mi][ni] = __builtin_amdgcn_mfma_f32_16x16x32_bf16(a[mi], b[ni], acc[mi][ni],0,0,0);
                }
            }
            float ab4[4], av4[4];
            #pragma unroll
            for (int ni=0;ni<4;++ni){ ab4[ni] = ab[w*64+ni*16+ll]; av4[ni] = av[w*64+ni*16+ll]; }
            float lgt[4][4];
            #pragma unroll
            for (int mi=0;mi<4;++mi){
                #pragma unroll
                for (int r=0;r<4;++r) lgt[mi][r] = 0.f;
            }
            #pragma unroll
            for (int mi=0;mi<4;++mi){
                #pragma unroll
                for (int ni=0;ni<4;++ni){
                    f32x4 v = acc[mi][ni];
                    #pragma unroll
                    for (int r=0;r<4;++r) lgt[mi][r] += fmaxf(v[r]+ab4[ni],0.f)*av4[ni];
                }
            }
            #pragma unroll
            for (int mi=0;mi<4;++mi){
                #pragma unroll
                for (int r=0;r<4;++r){
                    float vv = lgt[mi][r];
                    vv += __shfl_xor(vv,1,64); vv += __shfl_xor(vv,2,64);
                    vv += __shfl_xor(vv,4,64); vv += __shfl_xor(vv,8,64);
                    lgt[mi][r] = vv;
                }
            }
            if (ll == 0){
                #pragma unroll
                for (int mi=0;mi<4;++mi){
                    #pragma unroll
                    for (int r=0;r<4;++r){
                        int node = mi*16 + lgp*4 + r;
                        *(float*)(sm + SCOL_OFF + (w*64+node)*4) = lgt[mi][r];
                    }
                }
            }
            __syncthreads();
            if (tid < 64){
                const float* red = (const float*)(sm + SCOL_OFF);
                float lv = red[tid] + red[64+tid] + red[128+tid] + red[192+tid];
                float v = (tid < 63) ? lv : -INFINITY;
                float m = v;
                #pragma unroll
                for (int off=32; off; off>>=1) m = fmaxf(m, __shfl_xor(m, off, 64));
                float e = (tid < 63) ? expf(v - m) : 0.f;
                float s = e;
                #pragma unroll
                for (int off=32; off; off>>=1) s += __shfl_xor(s, off, 64);
                *(float*)(sm + SCOL_OFF + 1024 + tid*4) = e / s;
            }
            __syncthreads();
            {
                const int c = tid;
                const float* alpha = (const float*)(sm + SCOL_OFF + 1024);
                float pool = 0.f;
                for (int r=0;r<63;++r) pool += alpha[r]*b2f(*(const u16*)(sm + srow_b(r,c)));
                long zb = (long)g*1024 + zoff;
                z[zb + c]       = pool;
                z[zb + 256 + c] = b2f(*(const u16*)(sm + srow_b(63,c)));
            }
            __syncthreads();
        }

        // ---------- S5 (layer 0 only): P1 = H1 @ w1b : Srow -> Scol (direct)
        if (layer == 0){
            f32x4 acc[4][4];
            #pragma unroll
            for (int i=0;i<4;++i){
                #pragma unroll
                for (int j=0;j<4;++j) acc[i][j] = zero4;
            }
            for (int t=0;t<8;++t){
                const u16* ch = wb_w1b + ((t*4+w)<<11);
                const int k0 = t*32 + lgp*8;
                bf16x8 a[4], b[4];
                #pragma unroll
                for (int mi=0;mi<4;++mi) a[mi] = *(const bf16x8*)(sm + srow_b(mi*16+ll, k0));
                #pragma unroll
                for (int ni=0;ni<4;++ni) b[ni] = *(const bf16x8*)(ch + (ni*16+ll)*32 + lgp*8);
                #pragma unroll
                for (int mi=0;mi<4;++mi){
                    #pragma unroll
                    for (int ni=0;ni<4;++ni)
                        acc[mi][ni] = __builtin_amdgcn_mfma_f32_16x16x32_bf16(a[mi], b[ni], acc[mi][ni],0,0,0);
                }
            }
            __syncthreads();
            #pragma unroll
            for (int mi=0;mi<4;++mi){
                #pragma unroll
                for (int ni=0;ni<4;++ni){
                    int fo = w*64 + ni*16 + ll, nd0 = mi*16 + lgp*4;
                    f32x4 v = acc[mi][ni];
                    *(ushort4*)(sm + scol_b(fo,nd0)) = pack4(v[0],v[1],v[2],v[3]);
                }
            }
            __syncthreads();
        }
    }
}

// ---------------------------------------------------------------------------
// Weight pre-pass: f32 (K,256) row-major -> bf16 per-wave-slab K-tiled blob.
// ---------------------------------------------------------------------------
__global__ __launch_bounds__(256) void conv_wt_k(
    const float* __restrict__ src, u16* __restrict__ dst, int Ksrc, int Kt)
{
    int idx = blockIdx.x*256 + threadIdx.x;
    if (idx >= Kt*32*256) return;
    int k = idx >> 8, n = idx & 255;
    float v = (k < Ksrc) ? src[k*256 + n] : 0.f;
    int t = k>>5, kk = k&31, wv = n>>6, np = n&63;
    dst[((t*4+wv)<<11) + np*32 + kk] = f2b(v);
}

// ---------------------------------------------------------------------------
// BatchNorm stats over rows of z (2048 x 1024): scale/shift per column.
// ---------------------------------------------------------------------------
__global__ __launch_bounds__(256) void bnstats_k(
    const float* __restrict__ z, const float* __restrict__ gamma,
    const float* __restrict__ beta,
    float* __restrict__ scale, float* __restrict__ shift)
{
    const int c0 = blockIdx.x * 16;
    const int tid = threadIdx.x;
    const int c = c0 + (tid & 15), ph = tid >> 4;
    double s = 0.0, s2 = 0.0;
    for (int r = ph; r < 2048; r += 16) {
        float v = z[(long)r * 1024 + c];
        s += v; s2 += (double)v * v;
    }
    __shared__ double ss[16][17], ss2[16][17];
    ss[ph][tid & 15] = s; ss2[ph][tid & 15] = s2;
    __syncthreads();
    if (ph == 0) {
        double ts = 0.0, ts2 = 0.0;
        #pragma unroll
        for (int i = 0; i < 16; ++i) { ts += ss[i][tid & 15]; ts2 += ss2[i][tid & 15]; }
        double mu = ts / 2048.0;
        double var = ts2 / 2048.0 - mu * mu;
        float inv = (float)(1.0 / sqrt(var + 1e-5));
        float sc = gamma[c] * inv;
        scale[c] = sc;
        shift[c] = beta[c] - (float)mu * sc;
    }
}

// ---------------------------------------------------------------------------
// fc1: z2 = relu((z*scale+shift) @ fc1_w + fc1_b)   (2048x1024 @ 1024x256)
// ---------------------------------------------------------------------------
__global__ __launch_bounds__(256) void fc1_k(
    const float* __restrict__ A, const float* __restrict__ W,
    const float* __restrict__ bias, float* __restrict__ C,
    const float* __restrict__ scale, const float* __restrict__ shift)
{
    const int N = 256, K = 1024;
    __shared__ float As[16][68];
    __shared__ float Bs[16][68];
    const int tid = threadIdx.x;
    const int tx = tid & 15, ty = tid >> 4;
    const int n0 = blockIdx.x * 64, m0 = blockIdx.y * 64;
    const int li = tid >> 2, lk4 = tid & 3;
    const int bkk = tid >> 4, bj4 = tid & 15;
    const long arow = (long)(m0 + li) * K;

    float acc[4][4] = {};
    for (int k0 = 0; k0 < K; k0 += 16) {
        int kg = k0 + lk4 * 4;
        float4 av = *(const float4*)&A[arow + kg];
        float4 sc = *(const float4*)&scale[kg];
        float4 sh = *(const float4*)&shift[kg];
        av.x = av.x * sc.x + sh.x;
        av.y = av.y * sc.y + sh.y;
        av.z = av.z * sc.z + sh.z;
        av.w = av.w * sc.w + sh.w;
        As[lk4 * 4 + 0][li] = av.x;
        As[lk4 * 4 + 1][li] = av.y;
        As[lk4 * 4 + 2][li] = av.z;
        As[lk4 * 4 + 3][li] = av.w;
        float4 bv = *(const float4*)&W[(long)(k0 + bkk) * N + n0 + bj4 * 4];
        *(float4*)&Bs[bkk][bj4 * 4] = bv;
        __syncthreads();
        #pragma unroll
        for (int kk = 0; kk < 16; ++kk) {
            float4 a = *(const float4*)&As[kk][ty * 4];
            float4 b = *(const float4*)&Bs[kk][tx * 4];
            float ar[4] = {a.x, a.y, a.z, a.w};
            float br[4] = {b.x, b.y, b.z, b.w};
            #pragma unroll
            for (int i = 0; i < 4; ++i)
                #pragma unroll
                for (int j = 0; j < 4; ++j)
                    acc[i][j] += ar[i] * br[j];
        }
        __syncthreads();
    }
    #pragma unroll
    for (int i = 0; i < 4; ++i) {
        int r = m0 + ty * 4 + i;
        float v[4];
        #pragma unroll
        for (int j = 0; j < 4; ++j)
            v[j] = fmaxf(acc[i][j] + bias[n0 + tx * 4 + j], 0.f);
        *(float4*)&C[(long)r * N + n0 + tx * 4] = make_float4(v[0], v[1], v[2], v[3]);
    }
}

// ---------------------------------------------------------------------------
// Segment attention (no master) over z2 (128 x 16 x 256) -> pooled (128x256)
// ---------------------------------------------------------------------------
__global__ __launch_bounds__(256) void satt_k(
    const float* __restrict__ z2, const float* __restrict__ sw,
    const float* __restrict__ sb, const float* __restrict__ sv,
    float* __restrict__ pooled)
{
    const int b = blockIdx.x;
    const int tid = threadIdx.x;
    __shared__ float zs[16][256];
    for (int idx = tid; idx < 16 * 256; idx += 256) {
        int r = idx >> 8, c = idx & 255;
        zs[r][c] = z2[((long)b * 16 + r) * 256 + c];
    }
    __syncthreads();

    float acc[16] = {};
    for (int k = 0; k < 256; ++k) {
        float w = sw[k * 256 + tid];
        #pragma unroll
        for (int r = 0; r < 16; ++r) acc[r] += zs[r][k] * w;
    }
    const float sbv = sb[tid], svv = sv[tid];

    __shared__ float red[16][4];
    __shared__ float logit_s[16], alpha_s[16];
    const int warp = tid >> 6, lane = tid & 63;
    #pragma unroll
    for (int r = 0; r < 16; ++r) {
        float u = fmaxf(acc[r] + sbv, 0.f);
        float lv = u * svv;
        #pragma unroll
        for (int off = 32; off; off >>= 1) lv += __shfl_down(lv, off, 64);
        if (lane == 0) red[r][warp] = lv;
    }
    __syncthreads();
    if (tid < 16) logit_s[tid] = red[tid][0] + red[tid][1] + red[tid][2] + red[tid][3];
    __syncthreads();
    if (tid < 16) {
        float m = -INFINITY;
        #pragma unroll
        for (int i = 0; i < 16; ++i) m = fmaxf(m, logit_s[i]);
        float ssum = 0.f;
        #pragma unroll
        for (int i = 0; i < 16; ++i) ssum += expf(logit_s[i] - m);
        alpha_s[tid] = expf(logit_s[tid] - m) / ssum;
    }
    __syncthreads();
    float pacc = 0.f;
    #pragma unroll
    for (int r = 0; r < 16; ++r) pacc += alpha_s[r] * zs[r][tid];
    pooled[(long)b * 256 + tid] = pacc;
}

// ---------------------------------------------------------------------------
// Final head: relu(pooled@fc2+b2) -> @fc3+b3 -> log_softmax
// ---------------------------------------------------------------------------
__global__ __launch_bounds__(128) void final_k(
    const float* __restrict__ pooled,
    const float* __restrict__ w2, const float* __restrict__ b2,
    const float* __restrict__ w3, const float* __restrict__ b3,
    float* __restrict__ out)
{
    const int b = blockIdx.x, tid = threadIdx.x;
    __shared__ float ps[256], z3s[128], z4s[10];
    ps[tid]       = pooled[(long)b * 256 + tid];
    ps[tid + 128] = pooled[(long)b * 256 + tid + 128];
    __syncthreads();
    float acc = b2[tid];
    for (int k = 0; k < 256; ++k) acc += ps[k] * w2[k * 128 + tid];
    z3s[tid] = fmaxf(acc, 0.f);
    __syncthreads();
    if (tid < 10) {
        float a3 = b3[tid];
        for (int k = 0; k < 128; ++k) a3 += z3s[k] * w3[k * 10 + tid];
        z4s[tid] = a3;
    }
    __syncthreads();
    if (tid < 10) {
        float m = z4s[0];
        #pragma unroll
        for (int i = 1; i < 10; ++i) m = fmaxf(m, z4s[i]);
        float s = 0.f;
        #pragma unroll
        for (int i = 0; i < 10; ++i) s += expf(z4s[i] - m);
        out[b * 10 + tid] = z4s[tid] - m - logf(s);
    }
}

// ---------------------------------------------------------------------------
extern "C" void kernel_launch(void* const* d_in, const int* in_sizes, int n_in,
                              void* d_out, int out_size, void* d_ws, size_t ws_size,
                              hipStream_t stream)
{
    const int*   x      = (const int*)d_in[0];
    const float* adj    = (const float*)d_in[1];
    // d_in[2] = adj_s (unused), d_in[3]/d_in[4] = shape scalars
    const float* emb    = (const float*)d_in[5];
    const float* mp0_w1 = (const float*)d_in[6];
    const float* mp0_b1 = (const float*)d_in[7];
    const float* mp0_w2 = (const float*)d_in[8];
    const float* mp0_b2 = (const float*)d_in[9];
    const float* mp1_w1 = (const float*)d_in[10];
    const float* mp1_b1 = (const float*)d_in[11];
    const float* mp1_w2 = (const float*)d_in[12];
    const float* mp1_b2 = (const float*)d_in[13];
    const float* att0_w = (const float*)d_in[14];
    const float* att0_b = (const float*)d_in[15];
    const float* att0_v = (const float*)d_in[16];
    const float* att1_w = (const float*)d_in[17];
    const float* att1_b = (const float*)d_in[18];
    const float* att1_v = (const float*)d_in[19];
    const float* bn_g   = (const float*)d_in[20];
    const float* bn_b   = (const float*)d_in[21];
    const float* fc1_w  = (const float*)d_in[22];
    const float* fc1_b  = (const float*)d_in[23];
    const float* satt_w = (const float*)d_in[24];
    const float* satt_b = (const float*)d_in[25];
    const float* satt_v = (const float*)d_in[26];
    const float* fc2_w  = (const float*)d_in[27];
    const float* fc2_b  = (const float*)d_in[28];
    const float* fc3_w  = (const float*)d_in[29];
    const float* fc3_b  = (const float*)d_in[30];
    float* out = (float*)d_out;

    float* ws = (float*)d_ws;
    float* z       = ws;                    // 2048*1024
    float* z2      = z + 2048L * 1024;      // 2048*256
    float* scale   = z2 + 2048L * 256;      // 1024
    float* shiftv  = scale + 1024;          // 1024
    float* pooledS = shiftv + 1024;         // 128*256
    u16*   wbase   = (u16*)(pooledS + 128L*256);
    u16* wb_w1a = wbase;                    // 10 ktiles -> 81920 u16
    u16* wb_w2a = wb_w1a + 81920;           // 8 ktiles -> 65536 u16 each
    u16* wb_awa = wb_w2a + 65536;
    u16* wb_w1b = wb_awa + 65536;
    u16* wb_w2b = wb_w1b + 65536;
    u16* wb_awb = wb_w2b + 65536;
    // total ws ~ 11.4 MB

    // weight pre-pass (bf16, per-wave-slab K-tiled blobs)
    conv_wt_k<<<dim3(320), dim3(256), 0, stream>>>(mp0_w1, wb_w1a, 300, 10);
    conv_wt_k<<<dim3(256), dim3(256), 0, stream>>>(mp0_w2, wb_w2a, 256, 8);
    conv_wt_k<<<dim3(256), dim3(256), 0, stream>>>(att0_w, wb_awa, 256, 8);
    conv_wt_k<<<dim3(256), dim3(256), 0, stream>>>(mp1_w1, wb_w1b, 256, 8);
    conv_wt_k<<<dim3(256), dim3(256), 0, stream>>>(mp1_w2, wb_w2b, 256, 8);
    conv_wt_k<<<dim3(256), dim3(256), 0, stream>>>(att1_w, wb_awb, 256, 8);

    mega_k<<<dim3(2048), dim3(256), 0, stream>>>(
        x, adj, emb,
        wb_w1a, wb_w2a, wb_awa, wb_w1b, wb_w2b, wb_awb,
        mp0_b1, mp0_b2, att0_b, att0_v,
        mp1_b1, mp1_b2, att1_b, att1_v, z);

    bnstats_k<<<dim3(64), dim3(256), 0, stream>>>(z, bn_g, bn_b, scale, shiftv);
    fc1_k<<<dim3(4, 32), dim3(256), 0, stream>>>(z, fc1_w, fc1_b, z2, scale, shiftv);
    satt_k<<<dim3(128), dim3(256), 0, stream>>>(z2, satt_w, satt_b, satt_v, pooledS);
    final_k<<<dim3(128), dim3(128), 0, stream>>>(pooledS, fc2_w, fc2_b, fc3_w, fc3_b, out);
}

// Round 5
// 447.355 us; speedup vs baseline: 6.1759x; 1.1007x over previous
//
#include <hip/hip_runtime.h>
#include <math.h>

// Dims: V=50000 F=300 H=256 P=128 C=10  B=128 S=16 N=64  G=2048 T=131072

typedef unsigned short u16;
typedef __attribute__((ext_vector_type(8))) short bf16x8;
typedef __attribute__((ext_vector_type(4))) float f32x4;

__device__ __forceinline__ float b2f(u16 v){ return __uint_as_float(((unsigned)v)<<16); }
__device__ __forceinline__ u16 f2b(float f){
    unsigned u = __float_as_uint(f);
    return (u16)((u + 0x7FFFu + ((u>>16)&1u)) >> 16);   // RNE
}
__device__ __forceinline__ ushort4 pack4(float a,float b,float c,float d){
    ushort4 o; o.x=f2b(a); o.y=f2b(b); o.z=f2b(c); o.w=f2b(d); return o;
}
__device__ __forceinline__ bf16x8 cvt8(float4 lo, float4 hi){
    bf16x8 f;
    f[0]=(short)f2b(lo.x); f[1]=(short)f2b(lo.y); f[2]=(short)f2b(lo.z); f[3]=(short)f2b(lo.w);
    f[4]=(short)f2b(hi.x); f[5]=(short)f2b(hi.y); f[6]=(short)f2b(hi.z); f[7]=(short)f2b(hi.w);
    return f;
}

// LDS: Srow (64 nodes x 256 feat bf16, XOR-swizzled) at 0..32767
//      Scol (256 feat x 64 nodes bf16, XOR-swizzled) at 32768..65535
//      attention scratch (red[8][64], alpha[64], poolp[2][256]) aliases Scol.
#define SCOL_OFF 32768
__device__ __forceinline__ int srow_b(int nd, int f){
    return (nd*512 + f*2) ^ ((nd&7)<<4);
}
__device__ __forceinline__ int scol_b(int f, int nd){
    return SCOL_OFF + ((f*128 + nd*2) ^ ((f&7)<<4));
}

// ---------------------------------------------------------------------------
// Megakernel: one block per graph, 512 threads = 8 waves; each wave owns a
// 32-wide slab of the 256 dim. Hidden panel in LDS; all GEMMs on MFMA;
// weights read as bf16 fragments from pre-tiled global blobs (2KB/wave/t,
// coalesced; no weight LDS, no barriers inside K-loops).
// Blob layout (conv_all_k): chunk (t*8+slab)<<10 u16; elem [n_local]*32+kk.
// ---------------------------------------------------------------------------
__global__ __launch_bounds__(512, 4) void mega_k(
    const int* __restrict__ x, const float* __restrict__ adj,
    const float* __restrict__ emb,
    const u16* __restrict__ wb_w1a, const u16* __restrict__ wb_w2a,
    const u16* __restrict__ wb_awa, const u16* __restrict__ wb_w1b,
    const u16* __restrict__ wb_w2b, const u16* __restrict__ wb_awb,
    const float* __restrict__ b1a, const float* __restrict__ b2a,
    const float* __restrict__ aba, const float* __restrict__ ava,
    const float* __restrict__ b1b, const float* __restrict__ b2b,
    const float* __restrict__ abb, const float* __restrict__ avb,
    float* __restrict__ z)
{
    __shared__ __align__(16) char sm[65536];
    const int g = blockIdx.x, tid = threadIdx.x;
    const int w = tid>>6, l = tid&63, lgp = l>>4, ll = l&15;
    const f32x4 zero4 = {0.f,0.f,0.f,0.f};

    // ---------------- S1: P0 = emb[x_g] @ w1a  -> Scol  (K=320, zero-padded)
    {
        const float* rp[4];
        #pragma unroll
        for (int mi=0;mi<4;++mi) rp[mi] = emb + (long)x[g*64 + mi*16 + ll]*300;
        f32x4 acc[4][2];
        #pragma unroll
        for (int i=0;i<4;++i){
            acc[i][0] = zero4; acc[i][1] = zero4;
        }
        #pragma unroll
        for (int t=0;t<10;++t){
            const u16* ch = wb_w1a + ((t*8+w)<<10) + ll*32 + lgp*8;
            const int k0 = t*32 + lgp*8;
            bf16x8 a[4], b0, b1;
            #pragma unroll
            for (int mi=0;mi<4;++mi){
                float4 lo = (k0   < 300) ? *(const float4*)(rp[mi]+k0)   : make_float4(0.f,0.f,0.f,0.f);
                float4 hi = (k0+4 < 300) ? *(const float4*)(rp[mi]+k0+4) : make_float4(0.f,0.f,0.f,0.f);
                a[mi] = cvt8(lo, hi);
            }
            b0 = *(const bf16x8*)(ch);
            b1 = *(const bf16x8*)(ch + 512);
            #pragma unroll
            for (int mi=0;mi<4;++mi){
                acc[mi][0] = __builtin_amdgcn_mfma_f32_16x16x32_bf16(a[mi], b0, acc[mi][0],0,0,0);
                acc[mi][1] = __builtin_amdgcn_mfma_f32_16x16x32_bf16(a[mi], b1, acc[mi][1],0,0,0);
            }
        }
        #pragma unroll
        for (int mi=0;mi<4;++mi){
            #pragma unroll
            for (int ni=0;ni<2;++ni){
                int fo = w*32 + ni*16 + ll, nd0 = mi*16 + lgp*4;
                f32x4 v = acc[mi][ni];
                *(ushort4*)(sm + scol_b(fo,nd0)) = pack4(v[0],v[1],v[2],v[3]);
            }
        }
        __syncthreads();
    }

    const float* adjg = adj + (long)g*4096;

    // ========== layer loop (two MP+att layers) ==========
    #pragma unroll 1
    for (int layer=0; layer<2; ++layer){
        const u16* wb_w2 = layer ? wb_w2b : wb_w2a;
        const u16* wb_aw = layer ? wb_awb : wb_awa;
        const float* b1  = layer ? b1b : b1a;
        const float* b2  = layer ? b2b : b2a;
        const float* ab  = layer ? abb : aba;
        const float* av  = layer ? avb : ava;
        const int zoff   = layer ? 512 : 0;

        // ---------- S2: T = relu(adj @ P + b1) : Scol -> Srow (D[f][node])
        {
            f32x4 acc[2][4];
            #pragma unroll
            for (int j=0;j<4;++j){ acc[0][j] = zero4; acc[1][j] = zero4; }
            #pragma unroll
            for (int t=0;t<2;++t){
                const int k0 = t*32 + lgp*8;
                bf16x8 a0 = *(const bf16x8*)(sm + scol_b(w*32 +      ll, k0));
                bf16x8 a1 = *(const bf16x8*)(sm + scol_b(w*32 + 16 + ll, k0));
                bf16x8 b[4];
                #pragma unroll
                for (int ni=0;ni<4;++ni){
                    const float* p = adjg + (ni*16+ll)*64 + k0;
                    b[ni] = cvt8(*(const float4*)p, *(const float4*)(p+4));
                }
                #pragma unroll
                for (int ni=0;ni<4;++ni){
                    acc[0][ni] = __builtin_amdgcn_mfma_f32_16x16x32_bf16(a0, b[ni], acc[0][ni],0,0,0);
                    acc[1][ni] = __builtin_amdgcn_mfma_f32_16x16x32_bf16(a1, b[ni], acc[1][ni],0,0,0);
                }
            }
            #pragma unroll
            for (int mi=0;mi<2;++mi){
                int f0 = w*32 + mi*16 + lgp*4;
                float4 bi = *(const float4*)(b1 + f0);
                #pragma unroll
                for (int ni=0;ni<4;++ni){
                    int nd = ni*16 + ll;
                    f32x4 v = acc[mi][ni];
                    *(ushort4*)(sm + srow_b(nd, f0)) = pack4(
                        fmaxf(v[0]+bi.x,0.f), fmaxf(v[1]+bi.y,0.f),
                        fmaxf(v[2]+bi.z,0.f), fmaxf(v[3]+bi.w,0.f));
                }
            }
            __syncthreads();
        }

        // ---------- S3: H = relu(T @ w2 + b2) : Srow -> Srow (D[fo][node], in-place)
        {
            f32x4 acc[2][4];
            #pragma unroll
            for (int j=0;j<4;++j){ acc[0][j] = zero4; acc[1][j] = zero4; }
            #pragma unroll
            for (int t=0;t<8;++t){
                const u16* ch = wb_w2 + ((t*8+w)<<10) + ll*32 + lgp*8;
                const int k0 = t*32 + lgp*8;
                bf16x8 a0 = *(const bf16x8*)(ch);
                bf16x8 a1 = *(const bf16x8*)(ch + 512);
                bf16x8 b[4];
                #pragma unroll
                for (int ni=0;ni<4;++ni) b[ni] = *(const bf16x8*)(sm + srow_b(ni*16+ll, k0));
                #pragma unroll
                for (int ni=0;ni<4;++ni){
                    acc[0][ni] = __builtin_amdgcn_mfma_f32_16x16x32_bf16(a0, b[ni], acc[0][ni],0,0,0);
                    acc[1][ni] = __builtin_amdgcn_mfma_f32_16x16x32_bf16(a1, b[ni], acc[1][ni],0,0,0);
                }
            }
            __syncthreads();   // all waves done reading Srow before overwrite
            #pragma unroll
            for (int mi=0;mi<2;++mi){
                int f0 = w*32 + mi*16 + lgp*4;
                float4 bi = *(const float4*)(b2 + f0);
                #pragma unroll
                for (int ni=0;ni<4;++ni){
                    int nd = ni*16 + ll;
                    f32x4 v = acc[mi][ni];
                    *(ushort4*)(sm + srow_b(nd, f0)) = pack4(
                        fmaxf(v[0]+bi.x,0.f), fmaxf(v[1]+bi.y,0.f),
                        fmaxf(v[2]+bi.z,0.f), fmaxf(v[3]+bi.w,0.f));
                }
            }
            __syncthreads();
        }

        // ---------- S4: attention (U in registers; logits -> softmax -> pool)
        {
            f32x4 acc[4][2];
            #pragma unroll
            for (int i=0;i<4;++i){ acc[i][0] = zero4; acc[i][1] = zero4; }
            #pragma unroll
            for (int t=0;t<8;++t){
                const u16* ch = wb_aw + ((t*8+w)<<10) + ll*32 + lgp*8;
                const int k0 = t*32 + lgp*8;
                bf16x8 b0 = *(const bf16x8*)(ch);
                bf16x8 b1v = *(const bf16x8*)(ch + 512);
                bf16x8 a[4];
                #pragma unroll
                for (int mi=0;mi<4;++mi) a[mi] = *(const bf16x8*)(sm + srow_b(mi*16+ll, k0));
                #pragma unroll
                for (int mi=0;mi<4;++mi){
                    acc[mi][0] = __builtin_amdgcn_mfma_f32_16x16x32_bf16(a[mi], b0,  acc[mi][0],0,0,0);
                    acc[mi][1] = __builtin_amdgcn_mfma_f32_16x16x32_bf16(a[mi], b1v, acc[mi][1],0,0,0);
                }
            }
            float abv[2], avv[2];
            #pragma unroll
            for (int ni=0;ni<2;++ni){ abv[ni] = ab[w*32+ni*16+ll]; avv[ni] = av[w*32+ni*16+ll]; }
            float lgt[4][4];
            #pragma unroll
            for (int mi=0;mi<4;++mi){
                #pragma unroll
                for (int r=0;r<4;++r) lgt[mi][r] = 0.f;
            }
            #pragma unroll
            for (int mi=0;mi<4;++mi){
                #pragma unroll
                for (int ni=0;ni<2;++ni){
                    f32x4 v = acc[mi][ni];
                    #pragma unroll
                    for (int r=0;r<4;++r) lgt[mi][r] += fmaxf(v[r]+abv[ni],0.f)*avv[ni];
                }
            }
            #pragma unroll
            for (int mi=0;mi<4;++mi){
                #pragma unroll
                for (int r=0;r<4;++r){
                    float vv = lgt[mi][r];
                    vv += __shfl_xor(vv,1,64); vv += __shfl_xor(vv,2,64);
                    vv += __shfl_xor(vv,4,64); vv += __shfl_xor(vv,8,64);
                    lgt[mi][r] = vv;
                }
            }
            float* red   = (float*)(sm + SCOL_OFF);
            float* alpha = (float*)(sm + SCOL_OFF + 2048);
            float* poolp = (float*)(sm + SCOL_OFF + 2304);
            if (ll == 0){
                #pragma unroll
                for (int mi=0;mi<4;++mi){
                    #pragma unroll
                    for (int r=0;r<4;++r){
                        int node = mi*16 + lgp*4 + r;
                        red[w*64 + node] = lgt[mi][r];
                    }
                }
            }
            __syncthreads();
            if (tid < 64){
                float lv = 0.f;
                #pragma unroll
                for (int ww=0;ww<8;++ww) lv += red[ww*64 + tid];
                float v = (tid < 63) ? lv : -INFINITY;
                float m = v;
                #pragma unroll
                for (int off=32; off; off>>=1) m = fmaxf(m, __shfl_xor(m, off, 64));
                float e = (tid < 63) ? expf(v - m) : 0.f;
                float s = e;
                #pragma unroll
                for (int off=32; off; off>>=1) s += __shfl_xor(s, off, 64);
                alpha[tid] = e / s;
            }
            __syncthreads();
            {
                const int c = tid & 255, half = tid >> 8;
                const int r0v = half ? 32 : 0, r1v = half ? 63 : 32;
                float pool = 0.f;
                for (int r=r0v; r<r1v; ++r)
                    pool += alpha[r]*b2f(*(const u16*)(sm + srow_b(r,c)));
                poolp[half*256 + c] = pool;
            }
            __syncthreads();
            if (tid < 256){
                const int c = tid;
                long zb = (long)g*1024 + zoff;
                z[zb + c]       = poolp[c] + poolp[256+c];
                z[zb + 256 + c] = b2f(*(const u16*)(sm + srow_b(63,c)));
            }
            __syncthreads();
        }

        // ---------- S5 (layer 0 only): P1 = H1 @ w1b : Srow -> Scol
        if (layer == 0){
            f32x4 acc[4][2];
            #pragma unroll
            for (int i=0;i<4;++i){ acc[i][0] = zero4; acc[i][1] = zero4; }
            #pragma unroll
            for (int t=0;t<8;++t){
                const u16* ch = wb_w1b + ((t*8+w)<<10) + ll*32 + lgp*8;
                const int k0 = t*32 + lgp*8;
                bf16x8 b0 = *(const bf16x8*)(ch);
                bf16x8 b1v = *(const bf16x8*)(ch + 512);
                bf16x8 a[4];
                #pragma unroll
                for (int mi=0;mi<4;++mi) a[mi] = *(const bf16x8*)(sm + srow_b(mi*16+ll, k0));
                #pragma unroll
                for (int mi=0;mi<4;++mi){
                    acc[mi][0] = __builtin_amdgcn_mfma_f32_16x16x32_bf16(a[mi], b0,  acc[mi][0],0,0,0);
                    acc[mi][1] = __builtin_amdgcn_mfma_f32_16x16x32_bf16(a[mi], b1v, acc[mi][1],0,0,0);
                }
            }
            __syncthreads();   // alpha/pool reads done before Scol-scratch overwrite
            #pragma unroll
            for (int mi=0;mi<4;++mi){
                #pragma unroll
                for (int ni=0;ni<2;++ni){
                    int fo = w*32 + ni*16 + ll, nd0 = mi*16 + lgp*4;
                    f32x4 v = acc[mi][ni];
                    *(ushort4*)(sm + scol_b(fo,nd0)) = pack4(v[0],v[1],v[2],v[3]);
                }
            }
            __syncthreads();
        }
    }
}

// ---------------------------------------------------------------------------
// Weight pre-pass (all 6 weights in one launch): f32 (K,256) row-major ->
// bf16 8-slab K-tiled blobs, zero-padded K. Blobs contiguous from dst_base.
// ---------------------------------------------------------------------------
__global__ __launch_bounds__(256) void conv_all_k(
    const float* __restrict__ w1a, const float* __restrict__ w2a,
    const float* __restrict__ awa, const float* __restrict__ w1b,
    const float* __restrict__ w2b, const float* __restrict__ awb,
    u16* __restrict__ dst_base)
{
    long idx = (long)blockIdx.x*256 + threadIdx.x;
    if (idx >= 81920L + 5L*65536L) return;
    const float* src; u16* dst; int Ksrc; long rem;
    if (idx < 81920L){ src = w1a; dst = dst_base; Ksrc = 300; rem = idx; }
    else {
        long j = (idx - 81920L) / 65536L, r2 = (idx - 81920L) % 65536L;
        src = (j==0)?w2a:(j==1)?awa:(j==2)?w1b:(j==3)?w2b:awb;
        dst = dst_base + 81920L + j*65536L; Ksrc = 256; rem = r2;
    }
    int k = (int)(rem >> 8), n = (int)(rem & 255);
    float v = (k < Ksrc) ? src[k*256 + n] : 0.f;
    int t = k>>5, kk = k&31;
    dst[((t*8 + (n>>5))<<10) + (n&31)*32 + kk] = f2b(v);
}

// ---------------------------------------------------------------------------
// BatchNorm stats over rows of z (2048 x 1024): scale/shift per column.
// 256 blocks x 4 cols; 64 row-phases; 32 independent loads per thread.
// ---------------------------------------------------------------------------
__global__ __launch_bounds__(256) void bnstats_k(
    const float* __restrict__ z, const float* __restrict__ gamma,
    const float* __restrict__ beta,
    float* __restrict__ scale, float* __restrict__ shift)
{
    const int tid = threadIdx.x;
    const int cl = tid & 3, ph = tid >> 2;
    const int c = blockIdx.x * 4 + cl;
    double s = 0.0, s2 = 0.0;
    #pragma unroll 8
    for (int r = ph; r < 2048; r += 64) {
        float v = z[(long)r * 1024 + c];
        s += v; s2 += (double)v * v;
    }
    __shared__ double ss[256], ss2[256];
    ss[tid] = s; ss2[tid] = s2;
    __syncthreads();
    for (int off = 128; off >= 4; off >>= 1){
        if (tid < off){ ss[tid] += ss[tid+off]; ss2[tid] += ss2[tid+off]; }
        __syncthreads();
    }
    if (tid < 4){
        int cc = blockIdx.x * 4 + tid;
        double mu = ss[tid] / 2048.0;
        double var = ss2[tid] / 2048.0 - mu * mu;
        float inv = (float)(1.0 / sqrt(var + 1e-5));
        float sc = gamma[cc] * inv;
        scale[cc] = sc;
        shift[cc] = beta[cc] - (float)mu * sc;
    }
}

// ---------------------------------------------------------------------------
// fc1: z2 = relu((z*scale+shift) @ fc1_w + fc1_b)   (2048x1024 @ 1024x256)
// ---------------------------------------------------------------------------
__global__ __launch_bounds__(256) void fc1_k(
    const float* __restrict__ A, const float* __restrict__ W,
    const float* __restrict__ bias, float* __restrict__ C,
    const float* __restrict__ scale, const float* __restrict__ shift)
{
    const int N = 256, K = 1024;
    __shared__ float As[16][68];
    __shared__ float Bs[16][68];
    const int tid = threadIdx.x;
    const int tx = tid & 15, ty = tid >> 4;
    const int n0 = blockIdx.x * 64, m0 = blockIdx.y * 64;
    const int li = tid >> 2, lk4 = tid & 3;
    const int bkk = tid >> 4, bj4 = tid & 15;
    const long arow = (long)(m0 + li) * K;

    float acc[4][4] = {};
    for (int k0 = 0; k0 < K; k0 += 16) {
        int kg = k0 + lk4 * 4;
        float4 av = *(const float4*)&A[arow + kg];
        float4 sc = *(const float4*)&scale[kg];
        float4 sh = *(const float4*)&shift[kg];
        av.x = av.x * sc.x + sh.x;
        av.y = av.y * sc.y + sh.y;
        av.z = av.z * sc.z + sh.z;
        av.w = av.w * sc.w + sh.w;
        As[lk4 * 4 + 0][li] = av.x;
        As[lk4 * 4 + 1][li] = av.y;
        As[lk4 * 4 + 2][li] = av.z;
        As[lk4 * 4 + 3][li] = av.w;
        float4 bv = *(const float4*)&W[(long)(k0 + bkk) * N + n0 + bj4 * 4];
        *(float4*)&Bs[bkk][bj4 * 4] = bv;
        __syncthreads();
        #pragma unroll
        for (int kk = 0; kk < 16; ++kk) {
            float4 a = *(const float4*)&As[kk][ty * 4];
            float4 b = *(const float4*)&Bs[kk][tx * 4];
            float ar[4] = {a.x, a.y, a.z, a.w};
            float br[4] = {b.x, b.y, b.z, b.w};
            #pragma unroll
            for (int i = 0; i < 4; ++i)
                #pragma unroll
                for (int j = 0; j < 4; ++j)
                    acc[i][j] += ar[i] * br[j];
        }
        __syncthreads();
    }
    #pragma unroll
    for (int i = 0; i < 4; ++i) {
        int r = m0 + ty * 4 + i;
        float v[4];
        #pragma unroll
        for (int j = 0; j < 4; ++j)
            v[j] = fmaxf(acc[i][j] + bias[n0 + tx * 4 + j], 0.f);
        *(float4*)&C[(long)r * N + n0 + tx * 4] = make_float4(v[0], v[1], v[2], v[3]);
    }
}

// ---------------------------------------------------------------------------
// Segment attention (no master) over z2 (128 x 16 x 256) -> pooled (128x256)
// ---------------------------------------------------------------------------
__global__ __launch_bounds__(256) void satt_k(
    const float* __restrict__ z2, const float* __restrict__ sw,
    const float* __restrict__ sb, const float* __restrict__ sv,
    float* __restrict__ pooled)
{
    const int b = blockIdx.x;
    const int tid = threadIdx.x;
    __shared__ float zs[16][256];
    for (int idx = tid; idx < 16 * 256; idx += 256) {
        int r = idx >> 8, c = idx & 255;
        zs[r][c] = z2[((long)b * 16 + r) * 256 + c];
    }
    __syncthreads();

    float acc[16] = {};
    for (int k = 0; k < 256; ++k) {
        float w = sw[k * 256 + tid];
        #pragma unroll
        for (int r = 0; r < 16; ++r) acc[r] += zs[r][k] * w;
    }
    const float sbv = sb[tid], svv = sv[tid];

    __shared__ float red[16][4];
    __shared__ float logit_s[16], alpha_s[16];
    const int warp = tid >> 6, lane = tid & 63;
    #pragma unroll
    for (int r = 0; r < 16; ++r) {
        float u = fmaxf(acc[r] + sbv, 0.f);
        float lv = u * svv;
        #pragma unroll
        for (int off = 32; off; off >>= 1) lv += __shfl_down(lv, off, 64);
        if (lane == 0) red[r][warp] = lv;
    }
    __syncthreads();
    if (tid < 16) logit_s[tid] = red[tid][0] + red[tid][1] + red[tid][2] + red[tid][3];
    __syncthreads();
    if (tid < 16) {
        float m = -INFINITY;
        #pragma unroll
        for (int i = 0; i < 16; ++i) m = fmaxf(m, logit_s[i]);
        float ssum = 0.f;
        #pragma unroll
        for (int i = 0; i < 16; ++i) ssum += expf(logit_s[i] - m);
        alpha_s[tid] = expf(logit_s[tid] - m) / ssum;
    }
    __syncthreads();
    float pacc = 0.f;
    #pragma unroll
    for (int r = 0; r < 16; ++r) pacc += alpha_s[r] * zs[r][tid];
    pooled[(long)b * 256 + tid] = pacc;
}

// ---------------------------------------------------------------------------
// Final head: relu(pooled@fc2+b2) -> @fc3+b3 -> log_softmax
// ---------------------------------------------------------------------------
__global__ __launch_bounds__(128) void final_k(
    const float* __restrict__ pooled,
    const float* __restrict__ w2, const float* __restrict__ b2,
    const float* __restrict__ w3, const float* __restrict__ b3,
    float* __restrict__ out)
{
    const int b = blockIdx.x, tid = threadIdx.x;
    __shared__ float ps[256], z3s[128], z4s[10];
    ps[tid]       = pooled[(long)b * 256 + tid];
    ps[tid + 128] = pooled[(long)b * 256 + tid + 128];
    __syncthreads();
    float acc = b2[tid];
    for (int k = 0; k < 256; ++k) acc += ps[k] * w2[k * 128 + tid];
    z3s[tid] = fmaxf(acc, 0.f);
    __syncthreads();
    if (tid < 10) {
        float a3 = b3[tid];
        for (int k = 0; k < 128; ++k) a3 += z3s[k] * w3[k * 10 + tid];
        z4s[tid] = a3;
    }
    __syncthreads();
    if (tid < 10) {
        float m = z4s[0];
        #pragma unroll
        for (int i = 1; i < 10; ++i) m = fmaxf(m, z4s[i]);
        float s = 0.f;
        #pragma unroll
        for (int i = 0; i < 10; ++i) s += expf(z4s[i] - m);
        out[b * 10 + tid] = z4s[tid] - m - logf(s);
    }
}

// ---------------------------------------------------------------------------
extern "C" void kernel_launch(void* const* d_in, const int* in_sizes, int n_in,
                              void* d_out, int out_size, void* d_ws, size_t ws_size,
                              hipStream_t stream)
{
    const int*   x      = (const int*)d_in[0];
    const float* adj    = (const float*)d_in[1];
    // d_in[2] = adj_s (unused), d_in[3]/d_in[4] = shape scalars
    const float* emb    = (const float*)d_in[5];
    const float* mp0_w1 = (const float*)d_in[6];
    const float* mp0_b1 = (const float*)d_in[7];
    const float* mp0_w2 = (const float*)d_in[8];
    const float* mp0_b2 = (const float*)d_in[9];
    const float* mp1_w1 = (const float*)d_in[10];
    const float* mp1_b1 = (const float*)d_in[11];
    const float* mp1_w2 = (const float*)d_in[12];
    const float* mp1_b2 = (const float*)d_in[13];
    const float* att0_w = (const float*)d_in[14];
    const float* att0_b = (const float*)d_in[15];
    const float* att0_v = (const float*)d_in[16];
    const float* att1_w = (const float*)d_in[17];
    const float* att1_b = (const float*)d_in[18];
    const float* att1_v = (const float*)d_in[19];
    const float* bn_g   = (const float*)d_in[20];
    const float* bn_b   = (const float*)d_in[21];
    const float* fc1_w  = (const float*)d_in[22];
    const float* fc1_b  = (const float*)d_in[23];
    const float* satt_w = (const float*)d_in[24];
    const float* satt_b = (const float*)d_in[25];
    const float* satt_v = (const float*)d_in[26];
    const float* fc2_w  = (const float*)d_in[27];
    const float* fc2_b  = (const float*)d_in[28];
    const float* fc3_w  = (const float*)d_in[29];
    const float* fc3_b  = (const float*)d_in[30];
    float* out = (float*)d_out;

    float* ws = (float*)d_ws;
    float* z       = ws;                    // 2048*1024
    float* z2      = z + 2048L * 1024;      // 2048*256
    float* scale   = z2 + 2048L * 256;      // 1024
    float* shiftv  = scale + 1024;          // 1024
    float* pooledS = shiftv + 1024;         // 128*256
    u16*   wbase   = (u16*)(pooledS + 128L*256);
    u16* wb_w1a = wbase;                    // 81920 u16
    u16* wb_w2a = wb_w1a + 81920;           // 65536 u16 each below
    u16* wb_awa = wb_w2a + 65536;
    u16* wb_w1b = wb_awa + 65536;
    u16* wb_w2b = wb_w1b + 65536;
    u16* wb_awb = wb_w2b + 65536;
    // total ws ~ 11.4 MB

    conv_all_k<<<dim3(1600), dim3(256), 0, stream>>>(
        mp0_w1, mp0_w2, att0_w, mp1_w1, mp1_w2, att1_w, wbase);

    mega_k<<<dim3(2048), dim3(512), 0, stream>>>(
        x, adj, emb,
        wb_w1a, wb_w2a, wb_awa, wb_w1b, wb_w2b, wb_awb,
        mp0_b1, mp0_b2, att0_b, att0_v,
        mp1_b1, mp1_b2, att1_b, att1_v, z);

    bnstats_k<<<dim3(256), dim3(256), 0, stream>>>(z, bn_g, bn_b, scale, shiftv);
    fc1_k<<<dim3(4, 32), dim3(256), 0, stream>>>(z, fc1_w, fc1_b, z2, scale, shiftv);
    satt_k<<<dim3(128), dim3(256), 0, stream>>>(z2, satt_w, satt_b, satt_v, pooledS);
    final_k<<<dim3(128), dim3(128), 0, stream>>>(pooledS, fc2_w, fc2_b, fc3_w, fc3_b, out);
}

// Round 6
// 386.906 us; speedup vs baseline: 7.1408x; 1.1562x over previous
//
#include <hip/hip_runtime.h>
#include <math.h>

// Dims: V=50000 F=300 H=256 P=128 C=10  B=128 S=16 N=64  G=2048 T=131072

typedef unsigned short u16;
typedef __attribute__((ext_vector_type(8))) short bf16x8;
typedef __attribute__((ext_vector_type(4))) float f32x4;

__device__ __forceinline__ float b2f(u16 v){ return __uint_as_float(((unsigned)v)<<16); }
__device__ __forceinline__ u16 f2b(float f){
    unsigned u = __float_as_uint(f);
    return (u16)((u + 0x7FFFu + ((u>>16)&1u)) >> 16);   // RNE
}
__device__ __forceinline__ ushort4 pack4(float a,float b,float c,float d){
    ushort4 o; o.x=f2b(a); o.y=f2b(b); o.z=f2b(c); o.w=f2b(d); return o;
}
__device__ __forceinline__ bf16x8 cvt8(float4 lo, float4 hi){
    bf16x8 f;
    f[0]=(short)f2b(lo.x); f[1]=(short)f2b(lo.y); f[2]=(short)f2b(lo.z); f[3]=(short)f2b(lo.w);
    f[4]=(short)f2b(hi.x); f[5]=(short)f2b(hi.y); f[6]=(short)f2b(hi.z); f[7]=(short)f2b(hi.w);
    return f;
}

// LDS: Srow (64 nodes x 256 feat bf16, XOR-swizzled) at 0..32767
//      Scol (256 feat x 64 nodes bf16, XOR-swizzled) at 32768..65535
//      S1 emb staging double-buffer (2 x 4KB) aliases Srow[0:8192) (dead in S1).
//      attention scratch (red[8][64], alpha[64], poolp[2][256]) aliases Scol.
#define SCOL_OFF 32768
__device__ __forceinline__ int srow_b(int nd, int f){
    return (nd*512 + f*2) ^ ((nd&7)<<4);
}
__device__ __forceinline__ int scol_b(int f, int nd){
    return SCOL_OFF + ((f*128 + nd*2) ^ ((f&7)<<4));
}

// ---------------------------------------------------------------------------
// Megakernel: one block per graph, 512 threads = 8 waves; each wave owns a
// 32-wide slab of the 256 dim. Hidden panel in LDS; all GEMMs on MFMA;
// weights read as bf16 fragments from pre-tiled global blobs with explicit
// 1-deep prefetch; emb gather staged through LDS (1 coalesced load/thread/t).
// Blob layout (conv_all_k): chunk (t*8+slab)<<10 u16; elem [n_local]*32+kk.
// ---------------------------------------------------------------------------
__global__ __launch_bounds__(512, 4) void mega_k(
    const int* __restrict__ x, const float* __restrict__ adj,
    const float* __restrict__ emb,
    const u16* __restrict__ wb_w1a, const u16* __restrict__ wb_w2a,
    const u16* __restrict__ wb_awa, const u16* __restrict__ wb_w1b,
    const u16* __restrict__ wb_w2b, const u16* __restrict__ wb_awb,
    const float* __restrict__ b1a, const float* __restrict__ b2a,
    const float* __restrict__ aba, const float* __restrict__ ava,
    const float* __restrict__ b1b, const float* __restrict__ b2b,
    const float* __restrict__ abb, const float* __restrict__ avb,
    float* __restrict__ z)
{
    __shared__ __align__(16) char sm[65536];
    const int g = blockIdx.x, tid = threadIdx.x;
    const int w = tid>>6, l = tid&63, lgp = l>>4, ll = l&15;
    const f32x4 zero4 = {0.f,0.f,0.f,0.f};

    // ---------------- S1: P0 = emb[x_g] @ w1a  -> Scol  (K=320, zero-padded)
    {
        const int r  = tid >> 3;          // node 0..63
        const int kc = (tid & 7) * 4;     // k-chunk within 32
        const long xr = (long)x[g*64 + r] * 300;
        float4 pv = *(const float4*)(emb + xr + kc);      // t=0 tile
        const u16* chw = wb_w1a + (w<<10) + ll*32 + lgp*8;
        bf16x8 w0 = *(const bf16x8*)(chw);
        bf16x8 w1 = *(const bf16x8*)(chw + 512);

        f32x4 acc[4][2];
        #pragma unroll
        for (int i=0;i<4;++i){ acc[i][0] = zero4; acc[i][1] = zero4; }

        #pragma unroll
        for (int t=0;t<10;++t){
            float4 cur = pv;
            bf16x8 cw0 = w0, cw1 = w1;
            if (t < 9){
                int kn = (t+1)*32 + kc;
                pv = (kn + 4 <= 300) ? *(const float4*)(emb + xr + kn)
                                     : make_float4(0.f,0.f,0.f,0.f);
                const u16* nx = chw + (t+1)*8192;
                w0 = *(const bf16x8*)(nx);
                w1 = *(const bf16x8*)(nx + 512);
            }
            // stage this t-tile (64 nodes x 32 k, bf16) into EMB buf t&1
            *(ushort4*)(sm + (t&1)*4096 + r*64 + kc*2) =
                pack4(cur.x, cur.y, cur.z, cur.w);
            __syncthreads();
            const char* eb = sm + (t&1)*4096;
            bf16x8 a[4];
            #pragma unroll
            for (int mi=0;mi<4;++mi)
                a[mi] = *(const bf16x8*)(eb + (mi*16+ll)*64 + lgp*16);
            #pragma unroll
            for (int mi=0;mi<4;++mi){
                acc[mi][0] = __builtin_amdgcn_mfma_f32_16x16x32_bf16(a[mi], cw0, acc[mi][0],0,0,0);
                acc[mi][1] = __builtin_amdgcn_mfma_f32_16x16x32_bf16(a[mi], cw1, acc[mi][1],0,0,0);
            }
        }
        #pragma unroll
        for (int mi=0;mi<4;++mi){
            #pragma unroll
            for (int ni=0;ni<2;++ni){
                int fo = w*32 + ni*16 + ll, nd0 = mi*16 + lgp*4;
                f32x4 v = acc[mi][ni];
                *(ushort4*)(sm + scol_b(fo,nd0)) = pack4(v[0],v[1],v[2],v[3]);
            }
        }
        __syncthreads();
    }

    const float* adjg = adj + (long)g*4096;

    // ========== layer loop (two MP+att layers) ==========
    #pragma unroll 1
    for (int layer=0; layer<2; ++layer){
        const u16* wb_w2 = layer ? wb_w2b : wb_w2a;
        const u16* wb_aw = layer ? wb_awb : wb_awa;
        const float* b1  = layer ? b1b : b1a;
        const float* b2  = layer ? b2b : b2a;
        const float* ab  = layer ? abb : aba;
        const float* av  = layer ? avb : ava;
        const int zoff   = layer ? 512 : 0;

        // ---------- S2: T = relu(adj @ P + b1) : Scol -> Srow (D[f][node])
        {
            f32x4 acc[2][4];
            #pragma unroll
            for (int j=0;j<4;++j){ acc[0][j] = zero4; acc[1][j] = zero4; }
            #pragma unroll
            for (int t=0;t<2;++t){
                const int k0 = t*32 + lgp*8;
                bf16x8 a0 = *(const bf16x8*)(sm + scol_b(w*32 +      ll, k0));
                bf16x8 a1 = *(const bf16x8*)(sm + scol_b(w*32 + 16 + ll, k0));
                bf16x8 b[4];
                #pragma unroll
                for (int ni=0;ni<4;++ni){
                    const float* p = adjg + (ni*16+ll)*64 + k0;
                    b[ni] = cvt8(*(const float4*)p, *(const float4*)(p+4));
                }
                #pragma unroll
                for (int ni=0;ni<4;++ni){
                    acc[0][ni] = __builtin_amdgcn_mfma_f32_16x16x32_bf16(a0, b[ni], acc[0][ni],0,0,0);
                    acc[1][ni] = __builtin_amdgcn_mfma_f32_16x16x32_bf16(a1, b[ni], acc[1][ni],0,0,0);
                }
            }
            #pragma unroll
            for (int mi=0;mi<2;++mi){
                int f0 = w*32 + mi*16 + lgp*4;
                float4 bi = *(const float4*)(b1 + f0);
                #pragma unroll
                for (int ni=0;ni<4;++ni){
                    int nd = ni*16 + ll;
                    f32x4 v = acc[mi][ni];
                    *(ushort4*)(sm + srow_b(nd, f0)) = pack4(
                        fmaxf(v[0]+bi.x,0.f), fmaxf(v[1]+bi.y,0.f),
                        fmaxf(v[2]+bi.z,0.f), fmaxf(v[3]+bi.w,0.f));
                }
            }
            __syncthreads();
        }

        // ---------- S3: H = relu(T @ w2 + b2) : Srow -> Srow (in-place)
        {
            f32x4 acc[2][4];
            #pragma unroll
            for (int j=0;j<4;++j){ acc[0][j] = zero4; acc[1][j] = zero4; }
            const u16* chw = wb_w2 + (w<<10) + ll*32 + lgp*8;
            bf16x8 w0 = *(const bf16x8*)(chw);
            bf16x8 w1 = *(const bf16x8*)(chw + 512);
            #pragma unroll
            for (int t=0;t<8;++t){
                bf16x8 cw0 = w0, cw1 = w1;
                if (t < 7){
                    const u16* nx = chw + (t+1)*8192;
                    w0 = *(const bf16x8*)(nx);
                    w1 = *(const bf16x8*)(nx + 512);
                }
                const int k0 = t*32 + lgp*8;
                bf16x8 b[4];
                #pragma unroll
                for (int ni=0;ni<4;++ni) b[ni] = *(const bf16x8*)(sm + srow_b(ni*16+ll, k0));
                #pragma unroll
                for (int ni=0;ni<4;++ni){
                    acc[0][ni] = __builtin_amdgcn_mfma_f32_16x16x32_bf16(cw0, b[ni], acc[0][ni],0,0,0);
                    acc[1][ni] = __builtin_amdgcn_mfma_f32_16x16x32_bf16(cw1, b[ni], acc[1][ni],0,0,0);
                }
            }
            __syncthreads();   // all waves done reading Srow before overwrite
            #pragma unroll
            for (int mi=0;mi<2;++mi){
                int f0 = w*32 + mi*16 + lgp*4;
                float4 bi = *(const float4*)(b2 + f0);
                #pragma unroll
                for (int ni=0;ni<4;++ni){
                    int nd = ni*16 + ll;
                    f32x4 v = acc[mi][ni];
                    *(ushort4*)(sm + srow_b(nd, f0)) = pack4(
                        fmaxf(v[0]+bi.x,0.f), fmaxf(v[1]+bi.y,0.f),
                        fmaxf(v[2]+bi.z,0.f), fmaxf(v[3]+bi.w,0.f));
                }
            }
            __syncthreads();
        }

        // ---------- S4: attention (U in registers; logits -> softmax -> pool)
        {
            f32x4 acc[4][2];
            #pragma unroll
            for (int i=0;i<4;++i){ acc[i][0] = zero4; acc[i][1] = zero4; }
            const u16* chw = wb_aw + (w<<10) + ll*32 + lgp*8;
            bf16x8 w0 = *(const bf16x8*)(chw);
            bf16x8 w1 = *(const bf16x8*)(chw + 512);
            #pragma unroll
            for (int t=0;t<8;++t){
                bf16x8 cw0 = w0, cw1 = w1;
                if (t < 7){
                    const u16* nx = chw + (t+1)*8192;
                    w0 = *(const bf16x8*)(nx);
                    w1 = *(const bf16x8*)(nx + 512);
                }
                const int k0 = t*32 + lgp*8;
                bf16x8 a[4];
                #pragma unroll
                for (int mi=0;mi<4;++mi) a[mi] = *(const bf16x8*)(sm + srow_b(mi*16+ll, k0));
                #pragma unroll
                for (int mi=0;mi<4;++mi){
                    acc[mi][0] = __builtin_amdgcn_mfma_f32_16x16x32_bf16(a[mi], cw0, acc[mi][0],0,0,0);
                    acc[mi][1] = __builtin_amdgcn_mfma_f32_16x16x32_bf16(a[mi], cw1, acc[mi][1],0,0,0);
                }
            }
            float abv[2], avv[2];
            #pragma unroll
            for (int ni=0;ni<2;++ni){ abv[ni] = ab[w*32+ni*16+ll]; avv[ni] = av[w*32+ni*16+ll]; }
            float lgt[4][4];
            #pragma unroll
            for (int mi=0;mi<4;++mi){
                #pragma unroll
                for (int r=0;r<4;++r) lgt[mi][r] = 0.f;
            }
            #pragma unroll
            for (int mi=0;mi<4;++mi){
                #pragma unroll
                for (int ni=0;ni<2;++ni){
                    f32x4 v = acc[mi][ni];
                    #pragma unroll
                    for (int r=0;r<4;++r) lgt[mi][r] += fmaxf(v[r]+abv[ni],0.f)*avv[ni];
                }
            }
            #pragma unroll
            for (int mi=0;mi<4;++mi){
                #pragma unroll
                for (int r=0;r<4;++r){
                    float vv = lgt[mi][r];
                    vv += __shfl_xor(vv,1,64); vv += __shfl_xor(vv,2,64);
                    vv += __shfl_xor(vv,4,64); vv += __shfl_xor(vv,8,64);
                    lgt[mi][r] = vv;
                }
            }
            float* red   = (float*)(sm + SCOL_OFF);
            float* alpha = (float*)(sm + SCOL_OFF + 2048);
            float* poolp = (float*)(sm + SCOL_OFF + 2304);
            if (ll == 0){
                #pragma unroll
                for (int mi=0;mi<4;++mi){
                    #pragma unroll
                    for (int r=0;r<4;++r){
                        int node = mi*16 + lgp*4 + r;
                        red[w*64 + node] = lgt[mi][r];
                    }
                }
            }
            __syncthreads();
            if (tid < 64){
                float lv = 0.f;
                #pragma unroll
                for (int ww=0;ww<8;++ww) lv += red[ww*64 + tid];
                float v = (tid < 63) ? lv : -INFINITY;
                float m = v;
                #pragma unroll
                for (int off=32; off; off>>=1) m = fmaxf(m, __shfl_xor(m, off, 64));
                float e = (tid < 63) ? expf(v - m) : 0.f;
                float s = e;
                #pragma unroll
                for (int off=32; off; off>>=1) s += __shfl_xor(s, off, 64);
                alpha[tid] = e / s;
            }
            __syncthreads();
            {
                const int c = tid & 255, half = tid >> 8;
                const int r0v = half ? 32 : 0, r1v = half ? 63 : 32;
                float pool = 0.f;
                for (int r=r0v; r<r1v; ++r)
                    pool += alpha[r]*b2f(*(const u16*)(sm + srow_b(r,c)));
                poolp[half*256 + c] = pool;
            }
            __syncthreads();
            if (tid < 256){
                const int c = tid;
                long zb = (long)g*1024 + zoff;
                z[zb + c]       = poolp[c] + poolp[256+c];
                z[zb + 256 + c] = b2f(*(const u16*)(sm + srow_b(63,c)));
            }
            __syncthreads();
        }

        // ---------- S5 (layer 0 only): P1 = H1 @ w1b : Srow -> Scol
        if (layer == 0){
            f32x4 acc[4][2];
            #pragma unroll
            for (int i=0;i<4;++i){ acc[i][0] = zero4; acc[i][1] = zero4; }
            const u16* chw = wb_w1b + (w<<10) + ll*32 + lgp*8;
            bf16x8 w0 = *(const bf16x8*)(chw);
            bf16x8 w1 = *(const bf16x8*)(chw + 512);
            #pragma unroll
            for (int t=0;t<8;++t){
                bf16x8 cw0 = w0, cw1 = w1;
                if (t < 7){
                    const u16* nx = chw + (t+1)*8192;
                    w0 = *(const bf16x8*)(nx);
                    w1 = *(const bf16x8*)(nx + 512);
                }
                const int k0 = t*32 + lgp*8;
                bf16x8 a[4];
                #pragma unroll
                for (int mi=0;mi<4;++mi) a[mi] = *(const bf16x8*)(sm + srow_b(mi*16+ll, k0));
                #pragma unroll
                for (int mi=0;mi<4;++mi){
                    acc[mi][0] = __builtin_amdgcn_mfma_f32_16x16x32_bf16(a[mi], cw0, acc[mi][0],0,0,0);
                    acc[mi][1] = __builtin_amdgcn_mfma_f32_16x16x32_bf16(a[mi], cw1, acc[mi][1],0,0,0);
                }
            }
            __syncthreads();   // alpha/pool reads done before Scol-scratch overwrite
            #pragma unroll
            for (int mi=0;mi<4;++mi){
                #pragma unroll
                for (int ni=0;ni<2;++ni){
                    int fo = w*32 + ni*16 + ll, nd0 = mi*16 + lgp*4;
                    f32x4 v = acc[mi][ni];
                    *(ushort4*)(sm + scol_b(fo,nd0)) = pack4(v[0],v[1],v[2],v[3]);
                }
            }
            __syncthreads();
        }
    }
}

// ---------------------------------------------------------------------------
// Weight pre-pass (all 6 weights in one launch): f32 (K,256) row-major ->
// bf16 8-slab K-tiled blobs, zero-padded K. Blobs contiguous from dst_base.
// ---------------------------------------------------------------------------
__global__ __launch_bounds__(256) void conv_all_k(
    const float* __restrict__ w1a, const float* __restrict__ w2a,
    const float* __restrict__ awa, const float* __restrict__ w1b,
    const float* __restrict__ w2b, const float* __restrict__ awb,
    u16* __restrict__ dst_base)
{
    long idx = (long)blockIdx.x*256 + threadIdx.x;
    if (idx >= 81920L + 5L*65536L) return;
    const float* src; u16* dst; int Ksrc; long rem;
    if (idx < 81920L){ src = w1a; dst = dst_base; Ksrc = 300; rem = idx; }
    else {
        long j = (idx - 81920L) / 65536L, r2 = (idx - 81920L) % 65536L;
        src = (j==0)?w2a:(j==1)?awa:(j==2)?w1b:(j==3)?w2b:awb;
        dst = dst_base + 81920L + j*65536L; Ksrc = 256; rem = r2;
    }
    int k = (int)(rem >> 8), n = (int)(rem & 255);
    float v = (k < Ksrc) ? src[k*256 + n] : 0.f;
    int t = k>>5, kk = k&31;
    dst[((t*8 + (n>>5))<<10) + (n&31)*32 + kk] = f2b(v);
}

// ---------------------------------------------------------------------------
// BatchNorm stats over rows of z (2048 x 1024): scale/shift per column.
// ---------------------------------------------------------------------------
__global__ __launch_bounds__(256) void bnstats_k(
    const float* __restrict__ z, const float* __restrict__ gamma,
    const float* __restrict__ beta,
    float* __restrict__ scale, float* __restrict__ shift)
{
    const int tid = threadIdx.x;
    const int cl = tid & 3, ph = tid >> 2;
    const int c = blockIdx.x * 4 + cl;
    double s = 0.0, s2 = 0.0;
    #pragma unroll 8
    for (int r = ph; r < 2048; r += 64) {
        float v = z[(long)r * 1024 + c];
        s += v; s2 += (double)v * v;
    }
    __shared__ double ss[256], ss2[256];
    ss[tid] = s; ss2[tid] = s2;
    __syncthreads();
    for (int off = 128; off >= 4; off >>= 1){
        if (tid < off){ ss[tid] += ss[tid+off]; ss2[tid] += ss2[tid+off]; }
        __syncthreads();
    }
    if (tid < 4){
        int cc = blockIdx.x * 4 + tid;
        double mu = ss[tid] / 2048.0;
        double var = ss2[tid] / 2048.0 - mu * mu;
        float inv = (float)(1.0 / sqrt(var + 1e-5));
        float sc = gamma[cc] * inv;
        scale[cc] = sc;
        shift[cc] = beta[cc] - (float)mu * sc;
    }
}

// ---------------------------------------------------------------------------
// fc1: z2 = relu((z*scale+shift) @ fc1_w + fc1_b)   (2048x1024 @ 1024x256)
// ---------------------------------------------------------------------------
__global__ __launch_bounds__(256) void fc1_k(
    const float* __restrict__ A, const float* __restrict__ W,
    const float* __restrict__ bias, float* __restrict__ C,
    const float* __restrict__ scale, const float* __restrict__ shift)
{
    const int N = 256, K = 1024;
    __shared__ float As[16][68];
    __shared__ float Bs[16][68];
    const int tid = threadIdx.x;
    const int tx = tid & 15, ty = tid >> 4;
    const int n0 = blockIdx.x * 64, m0 = blockIdx.y * 64;
    const int li = tid >> 2, lk4 = tid & 3;
    const int bkk = tid >> 4, bj4 = tid & 15;
    const long arow = (long)(m0 + li) * K;

    float acc[4][4] = {};
    for (int k0 = 0; k0 < K; k0 += 16) {
        int kg = k0 + lk4 * 4;
        float4 av = *(const float4*)&A[arow + kg];
        float4 sc = *(const float4*)&scale[kg];
        float4 sh = *(const float4*)&shift[kg];
        av.x = av.x * sc.x + sh.x;
        av.y = av.y * sc.y + sh.y;
        av.z = av.z * sc.z + sh.z;
        av.w = av.w * sc.w + sh.w;
        As[lk4 * 4 + 0][li] = av.x;
        As[lk4 * 4 + 1][li] = av.y;
        As[lk4 * 4 + 2][li] = av.z;
        As[lk4 * 4 + 3][li] = av.w;
        float4 bv = *(const float4*)&W[(long)(k0 + bkk) * N + n0 + bj4 * 4];
        *(float4*)&Bs[bkk][bj4 * 4] = bv;
        __syncthreads();
        #pragma unroll
        for (int kk = 0; kk < 16; ++kk) {
            float4 a = *(const float4*)&As[kk][ty * 4];
            float4 b = *(const float4*)&Bs[kk][tx * 4];
            float ar[4] = {a.x, a.y, a.z, a.w};
            float br[4] = {b.x, b.y, b.z, b.w};
            #pragma unroll
            for (int i = 0; i < 4; ++i)
                #pragma unroll
                for (int j = 0; j < 4; ++j)
                    acc[i][j] += ar[i] * br[j];
        }
        __syncthreads();
    }
    #pragma unroll
    for (int i = 0; i < 4; ++i) {
        int r = m0 + ty * 4 + i;
        float v[4];
        #pragma unroll
        for (int j = 0; j < 4; ++j)
            v[j] = fmaxf(acc[i][j] + bias[n0 + tx * 4 + j], 0.f);
        *(float4*)&C[(long)r * N + n0 + tx * 4] = make_float4(v[0], v[1], v[2], v[3]);
    }
}

// ---------------------------------------------------------------------------
// Segment attention (no master) over z2 (128 x 16 x 256) -> pooled (128x256)
// ---------------------------------------------------------------------------
__global__ __launch_bounds__(256) void satt_k(
    const float* __restrict__ z2, const float* __restrict__ sw,
    const float* __restrict__ sb, const float* __restrict__ sv,
    float* __restrict__ pooled)
{
    const int b = blockIdx.x;
    const int tid = threadIdx.x;
    __shared__ float zs[16][256];
    for (int idx = tid; idx < 16 * 256; idx += 256) {
        int r = idx >> 8, c = idx & 255;
        zs[r][c] = z2[((long)b * 16 + r) * 256 + c];
    }
    __syncthreads();

    float acc[16] = {};
    for (int k = 0; k < 256; ++k) {
        float w = sw[k * 256 + tid];
        #pragma unroll
        for (int r = 0; r < 16; ++r) acc[r] += zs[r][k] * w;
    }
    const float sbv = sb[tid], svv = sv[tid];

    __shared__ float red[16][4];
    __shared__ float logit_s[16], alpha_s[16];
    const int warp = tid >> 6, lane = tid & 63;
    #pragma unroll
    for (int r = 0; r < 16; ++r) {
        float u = fmaxf(acc[r] + sbv, 0.f);
        float lv = u * svv;
        #pragma unroll
        for (int off = 32; off; off >>= 1) lv += __shfl_down(lv, off, 64);
        if (lane == 0) red[r][warp] = lv;
    }
    __syncthreads();
    if (tid < 16) logit_s[tid] = red[tid][0] + red[tid][1] + red[tid][2] + red[tid][3];
    __syncthreads();
    if (tid < 16) {
        float m = -INFINITY;
        #pragma unroll
        for (int i = 0; i < 16; ++i) m = fmaxf(m, logit_s[i]);
        float ssum = 0.f;
        #pragma unroll
        for (int i = 0; i < 16; ++i) ssum += expf(logit_s[i] - m);
        alpha_s[tid] = expf(logit_s[tid] - m) / ssum;
    }
    __syncthreads();
    float pacc = 0.f;
    #pragma unroll
    for (int r = 0; r < 16; ++r) pacc += alpha_s[r] * zs[r][tid];
    pooled[(long)b * 256 + tid] = pacc;
}

// ---------------------------------------------------------------------------
// Final head: relu(pooled@fc2+b2) -> @fc3+b3 -> log_softmax
// ---------------------------------------------------------------------------
__global__ __launch_bounds__(128) void final_k(
    const float* __restrict__ pooled,
    const float* __restrict__ w2, const float* __restrict__ b2,
    const float* __restrict__ w3, const float* __restrict__ b3,
    float* __restrict__ out)
{
    const int b = blockIdx.x, tid = threadIdx.x;
    __shared__ float ps[256], z3s[128], z4s[10];
    ps[tid]       = pooled[(long)b * 256 + tid];
    ps[tid + 128] = pooled[(long)b * 256 + tid + 128];
    __syncthreads();
    float acc = b2[tid];
    for (int k = 0; k < 256; ++k) acc += ps[k] * w2[k * 128 + tid];
    z3s[tid] = fmaxf(acc, 0.f);
    __syncthreads();
    if (tid < 10) {
        float a3 = b3[tid];
        for (int k = 0; k < 128; ++k) a3 += z3s[k] * w3[k * 10 + tid];
        z4s[tid] = a3;
    }
    __syncthreads();
    if (tid < 10) {
        float m = z4s[0];
        #pragma unroll
        for (int i = 1; i < 10; ++i) m = fmaxf(m, z4s[i]);
        float s = 0.f;
        #pragma unroll
        for (int i = 0; i < 10; ++i) s += expf(z4s[i] - m);
        out[b * 10 + tid] = z4s[tid] - m - logf(s);
    }
}

// ---------------------------------------------------------------------------
extern "C" void kernel_launch(void* const* d_in, const int* in_sizes, int n_in,
                              void* d_out, int out_size, void* d_ws, size_t ws_size,
                              hipStream_t stream)
{
    const int*   x      = (const int*)d_in[0];
    const float* adj    = (const float*)d_in[1];
    // d_in[2] = adj_s (unused), d_in[3]/d_in[4] = shape scalars
    const float* emb    = (const float*)d_in[5];
    const float* mp0_w1 = (const float*)d_in[6];
    const float* mp0_b1 = (const float*)d_in[7];
    const float* mp0_w2 = (const float*)d_in[8];
    const float* mp0_b2 = (const float*)d_in[9];
    const float* mp1_w1 = (const float*)d_in[10];
    const float* mp1_b1 = (const float*)d_in[11];
    const float* mp1_w2 = (const float*)d_in[12];
    const float* mp1_b2 = (const float*)d_in[13];
    const float* att0_w = (const float*)d_in[14];
    const float* att0_b = (const float*)d_in[15];
    const float* att0_v = (const float*)d_in[16];
    const float* att1_w = (const float*)d_in[17];
    const float* att1_b = (const float*)d_in[18];
    const float* att1_v = (const float*)d_in[19];
    const float* bn_g   = (const float*)d_in[20];
    const float* bn_b   = (const float*)d_in[21];
    const float* fc1_w  = (const float*)d_in[22];
    const float* fc1_b  = (const float*)d_in[23];
    const float* satt_w = (const float*)d_in[24];
    const float* satt_b = (const float*)d_in[25];
    const float* satt_v = (const float*)d_in[26];
    const float* fc2_w  = (const float*)d_in[27];
    const float* fc2_b  = (const float*)d_in[28];
    const float* fc3_w  = (const float*)d_in[29];
    const float* fc3_b  = (const float*)d_in[30];
    float* out = (float*)d_out;

    float* ws = (float*)d_ws;
    float* z       = ws;                    // 2048*1024
    float* z2      = z + 2048L * 1024;      // 2048*256
    float* scale   = z2 + 2048L * 256;      // 1024
    float* shiftv  = scale + 1024;          // 1024
    float* pooledS = shiftv + 1024;         // 128*256
    u16*   wbase   = (u16*)(pooledS + 128L*256);
    u16* wb_w1a = wbase;                    // 81920 u16
    u16* wb_w2a = wb_w1a + 81920;           // 65536 u16 each below
    u16* wb_awa = wb_w2a + 65536;
    u16* wb_w1b = wb_awa + 65536;
    u16* wb_w2b = wb_w1b + 65536;
    u16* wb_awb = wb_w2b + 65536;
    // total ws ~ 11.4 MB

    conv_all_k<<<dim3(1600), dim3(256), 0, stream>>>(
        mp0_w1, mp0_w2, att0_w, mp1_w1, mp1_w2, att1_w, wbase);

    mega_k<<<dim3(2048), dim3(512), 0, stream>>>(
        x, adj, emb,
        wb_w1a, wb_w2a, wb_awa, wb_w1b, wb_w2b, wb_awb,
        mp0_b1, mp0_b2, att0_b, att0_v,
        mp1_b1, mp1_b2, att1_b, att1_v, z);

    bnstats_k<<<dim3(256), dim3(256), 0, stream>>>(z, bn_g, bn_b, scale, shiftv);
    fc1_k<<<dim3(4, 32), dim3(256), 0, stream>>>(z, fc1_w, fc1_b, z2, scale, shiftv);
    satt_k<<<dim3(128), dim3(256), 0, stream>>>(z2, satt_w, satt_b, satt_v, pooledS);
    final_k<<<dim3(128), dim3(128), 0, stream>>>(pooledS, fc2_w, fc2_b, fc3_w, fc3_b, out);
}